// Round 1
// baseline (873.955 us; speedup 1.0000x reference)
//
#include <hip/hip_runtime.h>
#include <cstddef>

#define N_NODES 50000
#define N_EDGES 800000

// ---------------- workspace layout (element offsets, all %4==0 → 16B aligned)
// norm_src : ws[0          .. 50000)
// norm_dst : ws[50000      .. 100000)
// out_deg  : ws[100000     .. 150000)   (u32)
// in_deg   : ws[150000     .. 200000)   (u32)
// row_start: ws[200000     .. 250004)   (u32, 50001 used)
// counters : ws[250004     .. 300004)   (u32)
// edge_src : ws[300004     .. 1100004)  (int)
// hA       : ws[1100004    .. 7500004)  (50000*128 f32)
// hB       : ws[7500004    .. 13900004) (50000*128 f32)
// agg      : ws[13900004   .. 20300004) (50000*128 f32)
// mN       : ws[20300004   .. 20300068) (64 f32)
// total ≈ 81.2 MB

__global__ void deg_kernel(const int* __restrict__ src, const int* __restrict__ dst,
                           unsigned* __restrict__ outd, unsigned* __restrict__ ind) {
    int e = blockIdx.x * blockDim.x + threadIdx.x;
    if (e < N_EDGES) {
        atomicAdd(&outd[src[e]], 1u);
        atomicAdd(&ind[dst[e]], 1u);
    }
}

__global__ void norm_kernel(const unsigned* __restrict__ outd, const unsigned* __restrict__ ind,
                            float* __restrict__ ns, float* __restrict__ nd) {
    int n = blockIdx.x * blockDim.x + threadIdx.x;
    if (n < N_NODES) {
        unsigned od = outd[n]; if (od < 1u) od = 1u;
        unsigned id = ind[n];  if (id < 1u) id = 1u;
        ns[n] = 1.0f / sqrtf((float)od);
        nd[n] = 1.0f / sqrtf((float)id);
    }
}

// single-block exclusive scan of in_deg -> row_start[0..N_NODES]
__global__ void scan_kernel(const unsigned* __restrict__ deg, unsigned* __restrict__ rs) {
    __shared__ unsigned buf[1024];
    int tid = threadIdx.x;
    unsigned carry = 0;
    for (int base = 0; base < N_NODES; base += 1024) {
        int i = base + tid;
        unsigned v = (i < N_NODES) ? deg[i] : 0u;
        buf[tid] = v;
        __syncthreads();
        for (int off = 1; off < 1024; off <<= 1) {
            unsigned t = (tid >= off) ? buf[tid - off] : 0u;
            __syncthreads();
            buf[tid] += t;
            __syncthreads();
        }
        if (i < N_NODES) rs[i] = carry + buf[tid] - v;
        unsigned tot = buf[1023];
        __syncthreads();            // protect buf before next-iter overwrite
        carry += tot;               // same value in every thread
    }
    if (tid == 0) rs[N_NODES] = carry;
}

__global__ void copy_kernel(const unsigned* __restrict__ rs, unsigned* __restrict__ cnt) {
    int n = blockIdx.x * blockDim.x + threadIdx.x;
    if (n < N_NODES) cnt[n] = rs[n];
}

__global__ void fill_kernel(const int* __restrict__ src, const int* __restrict__ dst,
                            unsigned* __restrict__ cnt, int* __restrict__ edge_src) {
    int e = blockIdx.x * blockDim.x + threadIdx.x;
    if (e < N_EDGES) {
        unsigned pos = atomicAdd(&cnt[dst[e]], 1u);
        edge_src[pos] = src[e];
    }
}

// one block per dst node; 128 threads = one feature each; gather + sum (no atomics)
__global__ __launch_bounds__(128)
void agg_kernel(const float* __restrict__ h, const float* __restrict__ norm_src,
                const unsigned* __restrict__ rs, const int* __restrict__ edge_src,
                float* __restrict__ agg) {
    int n = blockIdx.x;
    int f = threadIdx.x;
    unsigned s0 = rs[n], s1 = rs[n + 1];
    float acc = 0.0f;
    for (unsigned i = s0; i < s1; ++i) {
        int s = edge_src[i];
        acc += norm_src[s] * h[(size_t)s * 128 + f];
    }
    agg[(size_t)n * 128 + f] = acc;
}

// C[n][j] = act( nd[n] * sum_k A[n][k]*W[k][j] + b[j] ), 16-row tiles, 256 thr
template <int NCOL, bool RELU>
__global__ __launch_bounds__(256)
void gemm_kernel(const float* __restrict__ A, const float* __restrict__ W,
                 const float* __restrict__ bias, const float* __restrict__ nd,
                 float* __restrict__ C) {
    constexpr int WS = NCOL + 4;         // padded LDS row stride
    __shared__ float Ws[128 * WS];
    __shared__ float As[16 * 132];
    int tid = threadIdx.x;
    int rowbase = blockIdx.x * 16;

    // stage W (row-major [k][NCOL]) into padded LDS
    for (int i = tid * 4; i < 128 * NCOL; i += 256 * 4) {
        int k = i / NCOL, c = i % NCOL;
        *(float4*)&Ws[k * WS + c] = *(const float4*)&W[i];
    }
    // stage A tile (contiguous 16x128 block)
    const float* Ablk = A + (size_t)rowbase * 128;
    for (int i = tid * 4; i < 16 * 128; i += 256 * 4) {
        int r = i >> 7, c = i & 127;
        *(float4*)&As[r * 132 + c] = *(const float4*)&Ablk[i];
    }
    __syncthreads();

    int r = tid >> 4;                 // 0..15
    int cb = (tid & 15) * 4;          // 0..60
    float4 acc0 = {0, 0, 0, 0};
    float4 acc1 = {0, 0, 0, 0};
    #pragma unroll 4
    for (int k = 0; k < 128; ++k) {
        float a = As[r * 132 + k];
        float4 w0 = *(const float4*)&Ws[k * WS + cb];
        acc0.x += a * w0.x; acc0.y += a * w0.y; acc0.z += a * w0.z; acc0.w += a * w0.w;
        if (NCOL == 128) {
            float4 w1 = *(const float4*)&Ws[k * WS + cb + 64];
            acc1.x += a * w1.x; acc1.y += a * w1.y; acc1.z += a * w1.z; acc1.w += a * w1.w;
        }
    }
    int row = rowbase + r;
    float s = nd[row];
    float4 o;
    o.x = s * acc0.x + bias[cb + 0];
    o.y = s * acc0.y + bias[cb + 1];
    o.z = s * acc0.z + bias[cb + 2];
    o.w = s * acc0.w + bias[cb + 3];
    if (RELU) { o.x = fmaxf(o.x, 0.f); o.y = fmaxf(o.y, 0.f); o.z = fmaxf(o.z, 0.f); o.w = fmaxf(o.w, 0.f); }
    *(float4*)&C[(size_t)row * NCOL + cb] = o;
    if (NCOL == 128) {
        float4 p;
        p.x = s * acc1.x + bias[cb + 64];
        p.y = s * acc1.y + bias[cb + 65];
        p.z = s * acc1.z + bias[cb + 66];
        p.w = s * acc1.w + bias[cb + 67];
        if (RELU) { p.x = fmaxf(p.x, 0.f); p.y = fmaxf(p.y, 0.f); p.z = fmaxf(p.z, 0.f); p.w = fmaxf(p.w, 0.f); }
        *(float4*)&C[(size_t)row * NCOL + cb + 64] = p;
    }
}

// PI[n] = dot(h4[n], Wp) + bp
__global__ void pi_kernel(const float* __restrict__ h4, const float* __restrict__ Wp,
                          const float* __restrict__ bp, float* __restrict__ out) {
    int n = blockIdx.x * blockDim.x + threadIdx.x;
    if (n >= N_NODES) return;
    const float4* hp = (const float4*)(h4 + (size_t)n * 64);
    float acc = 0.f;
    #pragma unroll
    for (int i = 0; i < 16; ++i) {
        float4 hv = hp[i];
        float4 wv = *(const float4*)&Wp[i * 4];
        acc += hv.x * wv.x + hv.y * wv.y + hv.z * wv.z + hv.w * wv.w;
    }
    out[n] = acc + bp[0];
}

// mN[f] += sum over nodes of h4[n][f]
__global__ __launch_bounds__(256)
void reduce_kernel(const float* __restrict__ h4, float* __restrict__ mN) {
    int f = threadIdx.x & 63;
    int rowInBlk = threadIdx.x >> 6;              // 0..3
    int row = blockIdx.x * 4 + rowInBlk;
    int stride = gridDim.x * 4;
    float acc = 0.f;
    for (int n = row; n < N_NODES; n += stride) acc += h4[(size_t)n * 64 + f];
    __shared__ float s[64];
    if (threadIdx.x < 64) s[threadIdx.x] = 0.f;
    __syncthreads();
    atomicAdd(&s[f], acc);
    __syncthreads();
    if (threadIdx.x < 64) atomicAdd(&mN[threadIdx.x], s[threadIdx.x]);
}

__global__ void v_kernel(const float* __restrict__ mN, const float* __restrict__ Wv,
                         const float* __restrict__ bv, float* __restrict__ out) {
    int f = threadIdx.x;  // 64 threads = 1 wave
    float v = mN[f] * Wv[f];
    #pragma unroll
    for (int off = 32; off > 0; off >>= 1) v += __shfl_down(v, off, 64);
    if (f == 0) out[N_NODES] = v + bv[0];
}

extern "C" void kernel_launch(void* const* d_in, const int* in_sizes, int n_in,
                              void* d_out, int out_size, void* d_ws, size_t ws_size,
                              hipStream_t stream) {
    const float* feat = (const float*)d_in[0];
    const int*   src  = (const int*)d_in[1];
    const int*   dst  = (const int*)d_in[2];
    const float* W0 = (const float*)d_in[3];  const float* b0 = (const float*)d_in[4];
    const float* W1 = (const float*)d_in[5];  const float* b1 = (const float*)d_in[6];
    const float* W2 = (const float*)d_in[7];  const float* b2 = (const float*)d_in[8];
    const float* W3 = (const float*)d_in[9];  const float* b3 = (const float*)d_in[10];
    const float* Wp = (const float*)d_in[11]; const float* bp = (const float*)d_in[12];
    const float* Wv = (const float*)d_in[13]; const float* bv = (const float*)d_in[14];
    float* out = (float*)d_out;
    float* ws  = (float*)d_ws;

    float*    norm_src = ws;
    float*    norm_dst = ws + 50000;
    unsigned* outd     = (unsigned*)(ws + 100000);
    unsigned* ind      = (unsigned*)(ws + 150000);
    unsigned* rs       = (unsigned*)(ws + 200000);
    unsigned* cnt      = (unsigned*)(ws + 250004);
    int*      edge_src = (int*)(ws + 300004);
    float*    hA       = ws + 1100004;
    float*    hB       = ws + 7500004;
    float*    agg      = ws + 13900004;
    float*    mN       = ws + 20300004;

    // zero deg arrays (contiguous) + mN accumulator
    hipMemsetAsync(ws + 100000, 0, 100000 * sizeof(float), stream);
    hipMemsetAsync(mN, 0, 64 * sizeof(float), stream);

    deg_kernel<<<3125, 256, 0, stream>>>(src, dst, outd, ind);
    norm_kernel<<<196, 256, 0, stream>>>(outd, ind, norm_src, norm_dst);
    scan_kernel<<<1, 1024, 0, stream>>>(ind, rs);
    copy_kernel<<<196, 256, 0, stream>>>(rs, cnt);
    fill_kernel<<<3125, 256, 0, stream>>>(src, dst, cnt, edge_src);

    // layer 0: feat -> hA
    agg_kernel<<<N_NODES, 128, 0, stream>>>(feat, norm_src, rs, edge_src, agg);
    gemm_kernel<128, true><<<3125, 256, 0, stream>>>(agg, W0, b0, norm_dst, hA);
    // layer 1: hA -> hB
    agg_kernel<<<N_NODES, 128, 0, stream>>>(hA, norm_src, rs, edge_src, agg);
    gemm_kernel<128, true><<<3125, 256, 0, stream>>>(agg, W1, b1, norm_dst, hB);
    // layer 2: hB -> hA
    agg_kernel<<<N_NODES, 128, 0, stream>>>(hB, norm_src, rs, edge_src, agg);
    gemm_kernel<128, true><<<3125, 256, 0, stream>>>(agg, W2, b2, norm_dst, hA);
    // layer 3: hA -> hB (64-wide, no relu)
    agg_kernel<<<N_NODES, 128, 0, stream>>>(hA, norm_src, rs, edge_src, agg);
    gemm_kernel<64, false><<<3125, 256, 0, stream>>>(agg, W3, b3, norm_dst, hB);

    // heads
    pi_kernel<<<196, 256, 0, stream>>>(hB, Wp, bp, out);
    reduce_kernel<<<128, 256, 0, stream>>>(hB, mN);
    v_kernel<<<1, 64, 0, stream>>>(mN, Wv, bv, out);
}

// Round 2
// 737.708 us; speedup vs baseline: 1.1847x; 1.1847x over previous
//
#include <hip/hip_runtime.h>
#include <cstddef>

#define N_NODES 50000
#define N_EDGES 800000

// ---------------- workspace layout (float-element offsets)
// ns       : 0        .. 50000
// nd       : 50000    .. 100000
// outd     : 100000   .. 150000  (u32)
// ind      : 150000   .. 200000  (u32)
// rs       : 200000   .. 250004  (u32, 50001 used)
// cnt      : 250004   .. 300004  (u32)
// mN       : 300004   .. 300080  (64 f32 used)
// edge_src : 300080   .. 1100080 (int)
// buf1     : 1100080  .. 7500080  (50000*128 f32)
// buf2     : 7500080  .. 13900080
// buf3     : 13900080 .. 20300080
// total = 81.2 MB

__global__ void deg_kernel(const int* __restrict__ src, const int* __restrict__ dst,
                           unsigned* __restrict__ outd, unsigned* __restrict__ ind) {
    int e = blockIdx.x * blockDim.x + threadIdx.x;
    if (e < N_EDGES) {
        atomicAdd(&outd[src[e]], 1u);
        atomicAdd(&ind[dst[e]], 1u);
    }
}

__global__ void norm_kernel(const unsigned* __restrict__ outd, const unsigned* __restrict__ ind,
                            float* __restrict__ ns, float* __restrict__ nd) {
    int n = blockIdx.x * blockDim.x + threadIdx.x;
    if (n < N_NODES) {
        unsigned od = outd[n]; if (od < 1u) od = 1u;
        unsigned id = ind[n];  if (id < 1u) id = 1u;
        ns[n] = 1.0f / sqrtf((float)od);
        nd[n] = 1.0f / sqrtf((float)id);
    }
}

// single-block chunked scan: thread t owns nodes [t*49, t*49+49)
__global__ __launch_bounds__(1024)
void scan_kernel(const unsigned* __restrict__ deg, unsigned* __restrict__ rs,
                 unsigned* __restrict__ cnt) {
    __shared__ unsigned buf[1024];
    const int CH = 49;                     // 1024*49 = 50176 >= 50000
    int tid = threadIdx.x;
    int lo = tid * CH;
    unsigned sum = 0;
    for (int j = 0; j < CH; ++j) {
        int i = lo + j;
        if (i < N_NODES) sum += deg[i];
    }
    buf[tid] = sum;
    __syncthreads();
    for (int off = 1; off < 1024; off <<= 1) {
        unsigned t = (tid >= off) ? buf[tid - off] : 0u;
        __syncthreads();
        buf[tid] += t;
        __syncthreads();
    }
    unsigned run = buf[tid] - sum;         // exclusive prefix of this chunk
    for (int j = 0; j < CH; ++j) {
        int i = lo + j;
        if (i < N_NODES) {
            rs[i] = run;
            cnt[i] = run;
            run += deg[i];
        }
    }
    if (tid == 1023) rs[N_NODES] = buf[1023];
}

__global__ void fill_kernel(const int* __restrict__ src, const int* __restrict__ dst,
                            unsigned* __restrict__ cnt, int* __restrict__ edge_src) {
    int e = blockIdx.x * blockDim.x + threadIdx.x;
    if (e < N_EDGES) {
        unsigned pos = atomicAdd(&cnt[dst[e]], 1u);
        edge_src[pos] = src[e];
    }
}

// hS = feat * ns[row]  (fold norm_src into the table once)
__global__ void prescale_kernel(const float* __restrict__ feat, const float* __restrict__ ns,
                                float* __restrict__ hS) {
    int i = blockIdx.x * blockDim.x + threadIdx.x;   // over N_NODES*32 float4s
    if (i < N_NODES * 32) {
        float s = ns[i >> 5];
        float4 v = *(const float4*)&feat[(size_t)i * 4];
        v.x *= s; v.y *= s; v.z *= s; v.w *= s;
        *(float4*)&hS[(size_t)i * 4] = v;
    }
}

// one WAVE per node (4 nodes / 256-thread block); edge loop unrolled x4 for MLP.
// WIDTH==128: lane covers 2 floats (512B row / wave-instr). WIDTH==64: 1 float.
template <int WIDTH>
__global__ __launch_bounds__(256)
void agg_kernel(const float* __restrict__ h, const unsigned* __restrict__ rs,
                const int* __restrict__ es, float* __restrict__ agg) {
    int node = blockIdx.x * 4 + (threadIdx.x >> 6);
    int lane = threadIdx.x & 63;
    unsigned s0 = rs[node], s1 = rs[node + 1];
    if (WIDTH == 128) {
        float2 acc = {0.f, 0.f};
        unsigned i = s0;
        for (; i + 4 <= s1; i += 4) {
            int e0 = es[i], e1 = es[i + 1], e2 = es[i + 2], e3 = es[i + 3];
            float2 v0 = *(const float2*)&h[(size_t)e0 * 128 + lane * 2];
            float2 v1 = *(const float2*)&h[(size_t)e1 * 128 + lane * 2];
            float2 v2 = *(const float2*)&h[(size_t)e2 * 128 + lane * 2];
            float2 v3 = *(const float2*)&h[(size_t)e3 * 128 + lane * 2];
            acc.x += (v0.x + v1.x) + (v2.x + v3.x);
            acc.y += (v0.y + v1.y) + (v2.y + v3.y);
        }
        for (; i < s1; ++i) {
            int e = es[i];
            float2 v = *(const float2*)&h[(size_t)e * 128 + lane * 2];
            acc.x += v.x; acc.y += v.y;
        }
        *(float2*)&agg[(size_t)node * 128 + lane * 2] = acc;
    } else {
        float acc = 0.f;
        unsigned i = s0;
        for (; i + 4 <= s1; i += 4) {
            int e0 = es[i], e1 = es[i + 1], e2 = es[i + 2], e3 = es[i + 3];
            float v0 = h[(size_t)e0 * 64 + lane];
            float v1 = h[(size_t)e1 * 64 + lane];
            float v2 = h[(size_t)e2 * 64 + lane];
            float v3 = h[(size_t)e3 * 64 + lane];
            acc += (v0 + v1) + (v2 + v3);
        }
        for (; i < s1; ++i) acc += h[(size_t)es[i] * 64 + lane];
        agg[(size_t)node * 64 + lane] = acc;
    }
}

// C = epilogue(A @ W). 128 rows/block, 512 threads, thread = 4 rows x (NCOL/16) cols.
// MODE 0: C = ns[row] * relu(nd[row]*acc + b[col])   (pre-scaled hidden layer)
// MODE 1: C = acc                                     (plain transform, layer-3 W)
template <int NCOL, int MODE>
__global__ __launch_bounds__(512)
void gemm_kernel(const float* __restrict__ A, const float* __restrict__ W,
                 const float* __restrict__ bias, const float* __restrict__ ns,
                 const float* __restrict__ nd, float* __restrict__ C) {
    __shared__ float Ws[128 * NCOL];
    __shared__ float As[128 * 130];      // +2 pad: banks (2r+k)%32 -> conflict-free
    int tid = threadIdx.x;
    int rowbase = blockIdx.x * 128;

    for (int i = tid; i < 128 * NCOL / 4; i += 512)
        *(float4*)&Ws[i * 4] = *(const float4*)&W[(size_t)i * 4];
    for (int i = tid; i < 128 * 32; i += 512) {
        int r = i >> 5, c4 = (i & 31) * 4;
        int row = rowbase + r;
        float4 v = {0.f, 0.f, 0.f, 0.f};
        if (row < N_NODES) v = *(const float4*)&A[(size_t)row * 128 + c4];
        *(float4*)&As[r * 130 + c4] = v;
    }
    __syncthreads();

    int cb = (tid & 15) * 4;             // 0..60
    int r0 = (tid >> 4) * 4;             // 0..124
    float4 acc[4][2];
    #pragma unroll
    for (int j = 0; j < 4; ++j) {
        acc[j][0] = make_float4(0.f, 0.f, 0.f, 0.f);
        acc[j][1] = make_float4(0.f, 0.f, 0.f, 0.f);
    }

    #pragma unroll 4
    for (int k = 0; k < 128; ++k) {
        float4 w0 = *(const float4*)&Ws[k * NCOL + cb];
        float4 w1;
        if (NCOL == 128) w1 = *(const float4*)&Ws[k * NCOL + cb + 64];
        #pragma unroll
        for (int j = 0; j < 4; ++j) {
            float a = As[(r0 + j) * 130 + k];
            acc[j][0].x += a * w0.x; acc[j][0].y += a * w0.y;
            acc[j][0].z += a * w0.z; acc[j][0].w += a * w0.w;
            if (NCOL == 128) {
                acc[j][1].x += a * w1.x; acc[j][1].y += a * w1.y;
                acc[j][1].z += a * w1.z; acc[j][1].w += a * w1.w;
            }
        }
    }

    #pragma unroll
    for (int j = 0; j < 4; ++j) {
        int row = rowbase + r0 + j;
        if (row >= N_NODES) break;
        if (MODE == 0) {
            float sd = nd[row], ss = ns[row];
            float4 o = acc[j][0];
            o.x = ss * fmaxf(sd * o.x + bias[cb + 0], 0.f);
            o.y = ss * fmaxf(sd * o.y + bias[cb + 1], 0.f);
            o.z = ss * fmaxf(sd * o.z + bias[cb + 2], 0.f);
            o.w = ss * fmaxf(sd * o.w + bias[cb + 3], 0.f);
            *(float4*)&C[(size_t)row * NCOL + cb] = o;
            if (NCOL == 128) {
                float4 p = acc[j][1];
                p.x = ss * fmaxf(sd * p.x + bias[cb + 64], 0.f);
                p.y = ss * fmaxf(sd * p.y + bias[cb + 65], 0.f);
                p.z = ss * fmaxf(sd * p.z + bias[cb + 66], 0.f);
                p.w = ss * fmaxf(sd * p.w + bias[cb + 67], 0.f);
                *(float4*)&C[(size_t)row * NCOL + cb + 64] = p;
            }
        } else {
            *(float4*)&C[(size_t)row * NCOL + cb] = acc[j][0];
            if (NCOL == 128) *(float4*)&C[(size_t)row * NCOL + cb + 64] = acc[j][1];
        }
    }
}

// fused heads: h4 = nd[n]*agg64[n] + b3;  PI[n] = h4.Wp + bp;  mN += h4 (partials)
__global__ __launch_bounds__(256)
void head_kernel(const float* __restrict__ agg64, const float* __restrict__ nd,
                 const float* __restrict__ b3, const float* __restrict__ Wp,
                 const float* __restrict__ bp, float* __restrict__ out,
                 float* __restrict__ mN) {
    __shared__ float s[64];
    int lane = threadIdx.x & 63;
    int sub = threadIdx.x >> 6;
    if (threadIdx.x < 64) s[threadIdx.x] = 0.f;
    __syncthreads();
    float wp = Wp[lane];
    float bb = b3[lane];
    float bpv = bp[0];
    float msum = 0.f;
    for (int n = blockIdx.x * 4 + sub; n < N_NODES; n += gridDim.x * 4) {
        float h = nd[n] * agg64[(size_t)n * 64 + lane] + bb;
        msum += h;
        float p = h * wp;
        #pragma unroll
        for (int off = 32; off; off >>= 1) p += __shfl_down(p, off, 64);
        if (lane == 0) out[n] = p + bpv;
    }
    atomicAdd(&s[lane], msum);
    __syncthreads();
    if (threadIdx.x < 64) atomicAdd(&mN[threadIdx.x], s[threadIdx.x]);
}

__global__ void v_kernel(const float* __restrict__ mN, const float* __restrict__ Wv,
                         const float* __restrict__ bv, float* __restrict__ out) {
    int f = threadIdx.x;  // 64 threads = 1 wave
    float v = mN[f] * Wv[f];
    #pragma unroll
    for (int off = 32; off; off >>= 1) v += __shfl_down(v, off, 64);
    if (f == 0) out[N_NODES] = v + bv[0];
}

extern "C" void kernel_launch(void* const* d_in, const int* in_sizes, int n_in,
                              void* d_out, int out_size, void* d_ws, size_t ws_size,
                              hipStream_t stream) {
    const float* feat = (const float*)d_in[0];
    const int*   src  = (const int*)d_in[1];
    const int*   dst  = (const int*)d_in[2];
    const float* W0 = (const float*)d_in[3];  const float* b0 = (const float*)d_in[4];
    const float* W1 = (const float*)d_in[5];  const float* b1 = (const float*)d_in[6];
    const float* W2 = (const float*)d_in[7];  const float* b2 = (const float*)d_in[8];
    const float* W3 = (const float*)d_in[9];  const float* b3 = (const float*)d_in[10];
    const float* Wp = (const float*)d_in[11]; const float* bp = (const float*)d_in[12];
    const float* Wv = (const float*)d_in[13]; const float* bv = (const float*)d_in[14];
    float* out = (float*)d_out;
    float* ws  = (float*)d_ws;

    float*    ns       = ws;
    float*    nd       = ws + 50000;
    unsigned* outd     = (unsigned*)(ws + 100000);
    unsigned* ind      = (unsigned*)(ws + 150000);
    unsigned* rs       = (unsigned*)(ws + 200000);
    unsigned* cnt      = (unsigned*)(ws + 250004);
    float*    mN       = ws + 300004;
    int*      es       = (int*)(ws + 300080);
    float*    buf1     = ws + 1100080;
    float*    buf2     = ws + 7500080;
    float*    buf3     = ws + 13900080;

    hipMemsetAsync(ws + 100000, 0, 100000 * sizeof(float), stream);   // outd+ind
    hipMemsetAsync(mN, 0, 64 * sizeof(float), stream);

    deg_kernel<<<3125, 256, 0, stream>>>(src, dst, outd, ind);
    norm_kernel<<<196, 256, 0, stream>>>(outd, ind, ns, nd);
    scan_kernel<<<1, 1024, 0, stream>>>(ind, rs, cnt);
    fill_kernel<<<3125, 256, 0, stream>>>(src, dst, cnt, es);

    prescale_kernel<<<6250, 256, 0, stream>>>(feat, ns, buf1);        // hS = ns*feat

    // layer 0
    agg_kernel<128><<<12500, 256, 0, stream>>>(buf1, rs, es, buf2);
    gemm_kernel<128, 0><<<391, 512, 0, stream>>>(buf2, W0, b0, ns, nd, buf3);
    // layer 1
    agg_kernel<128><<<12500, 256, 0, stream>>>(buf3, rs, es, buf2);
    gemm_kernel<128, 0><<<391, 512, 0, stream>>>(buf2, W1, b1, ns, nd, buf1);
    // layer 2
    agg_kernel<128><<<12500, 256, 0, stream>>>(buf1, rs, es, buf2);
    gemm_kernel<128, 0><<<391, 512, 0, stream>>>(buf2, W2, b2, ns, nd, buf3);  // h3s
    // layer 3: transform FIRST (128->64), then aggregate 64-wide
    gemm_kernel<64, 1><<<391, 512, 0, stream>>>(buf3, W3, b3, ns, nd, buf1);   // t = h3s@W3
    agg_kernel<64><<<12500, 256, 0, stream>>>(buf1, rs, es, buf2);

    // heads (h4 = nd*agg64 + b3 computed on the fly)
    head_kernel<<<196, 256, 0, stream>>>(buf2, nd, b3, Wp, bp, out, mN);
    v_kernel<<<1, 64, 0, stream>>>(mN, Wv, bv, out);
}

// Round 3
// 635.166 us; speedup vs baseline: 1.3759x; 1.1614x over previous
//
#include <hip/hip_runtime.h>
#include <cstddef>

#define N_NODES 50000
#define N_EDGES 800000

// ---------------- workspace layout (float-element offsets)
// ns       : 0        .. 50000
// nd       : 50000    .. 100000
// outd     : 100000   .. 150000  (u32; reused as bsum[196] after norm_kernel)
// ind      : 150000   .. 200000  (u32)
// rs       : 200000   .. 250004  (u32, 50001 used)
// cnt      : 250004   .. 300004  (u32)
// mN       : 300004   .. 300080  (64 f32 used)
// edge_src : 300080   .. 1100080 (int)
// buf1     : 1100080  .. 7500080  (50000*128 f32)
// buf2     : 7500080  .. 13900080
// buf3     : 13900080 .. 20300080

__global__ void deg_kernel(const int* __restrict__ src, const int* __restrict__ dst,
                           unsigned* __restrict__ outd, unsigned* __restrict__ ind) {
    int e = blockIdx.x * blockDim.x + threadIdx.x;
    if (e < N_EDGES) {
        atomicAdd(&outd[src[e]], 1u);
        atomicAdd(&ind[dst[e]], 1u);
    }
}

__global__ void norm_kernel(const unsigned* __restrict__ outd, const unsigned* __restrict__ ind,
                            float* __restrict__ ns, float* __restrict__ nd) {
    int n = blockIdx.x * blockDim.x + threadIdx.x;
    if (n < N_NODES) {
        unsigned od = outd[n]; if (od < 1u) od = 1u;
        unsigned id = ind[n];  if (id < 1u) id = 1u;
        ns[n] = 1.0f / sqrtf((float)od);
        nd[n] = 1.0f / sqrtf((float)id);
    }
}

// ---- hierarchical scan: per-block sums -> scan sums -> local scan + offset
__global__ __launch_bounds__(256)
void scan1_kernel(const unsigned* __restrict__ deg, unsigned* __restrict__ bsum) {
    __shared__ unsigned s[4];
    int i = blockIdx.x * 256 + threadIdx.x;
    unsigned v = (i < N_NODES) ? deg[i] : 0u;
    #pragma unroll
    for (int off = 32; off; off >>= 1) v += __shfl_down(v, off, 64);
    if ((threadIdx.x & 63) == 0) s[threadIdx.x >> 6] = v;
    __syncthreads();
    if (threadIdx.x == 0) bsum[blockIdx.x] = s[0] + s[1] + s[2] + s[3];
}

__global__ __launch_bounds__(256)
void scan2_kernel(unsigned* __restrict__ bsum, unsigned* __restrict__ rs) {
    __shared__ unsigned sb[256];
    int tid = threadIdx.x;
    unsigned v = (tid < 196) ? bsum[tid] : 0u;
    sb[tid] = v;
    __syncthreads();
    for (int off = 1; off < 256; off <<= 1) {
        unsigned t = (tid >= off) ? sb[tid - off] : 0u;
        __syncthreads();
        sb[tid] += t;
        __syncthreads();
    }
    if (tid < 196) bsum[tid] = sb[tid] - v;      // exclusive block offsets
    if (tid == 0) rs[N_NODES] = N_EDGES;         // total degree == edge count
}

__global__ __launch_bounds__(256)
void scan3_kernel(const unsigned* __restrict__ deg, const unsigned* __restrict__ bsum,
                  unsigned* __restrict__ rs, unsigned* __restrict__ cnt) {
    __shared__ unsigned sb[256];
    int tid = threadIdx.x;
    int i = blockIdx.x * 256 + tid;
    unsigned v = (i < N_NODES) ? deg[i] : 0u;
    sb[tid] = v;
    __syncthreads();
    for (int off = 1; off < 256; off <<= 1) {
        unsigned t = (tid >= off) ? sb[tid - off] : 0u;
        __syncthreads();
        sb[tid] += t;
        __syncthreads();
    }
    if (i < N_NODES) {
        unsigned r = bsum[blockIdx.x] + sb[tid] - v;
        rs[i] = r;
        cnt[i] = r;
    }
}

__global__ void fill_kernel(const int* __restrict__ src, const int* __restrict__ dst,
                            unsigned* __restrict__ cnt, int* __restrict__ edge_src) {
    int e = blockIdx.x * blockDim.x + threadIdx.x;
    if (e < N_EDGES) {
        unsigned pos = atomicAdd(&cnt[dst[e]], 1u);
        edge_src[pos] = src[e];
    }
}

// hS = feat * ns[row]
__global__ void prescale_kernel(const float* __restrict__ feat, const float* __restrict__ ns,
                                float* __restrict__ hS) {
    int i = blockIdx.x * blockDim.x + threadIdx.x;   // over N_NODES*32 float4s
    if (i < N_NODES * 32) {
        float s = ns[i >> 5];
        float4 v = *(const float4*)&feat[(size_t)i * 4];
        v.x *= s; v.y *= s; v.z *= s; v.w *= s;
        *(float4*)&hS[(size_t)i * 4] = v;
    }
}

// one WAVE per node; 32 lanes x float4 (or float2) cover a row, lane-half picks
// the edge -> 2 edges per pass, main loop 8 edges (4 independent loads/thread).
template <int WIDTH>
__global__ __launch_bounds__(256)
void agg_kernel(const float* __restrict__ h, const unsigned* __restrict__ rs,
                const int* __restrict__ es, float* __restrict__ agg) {
    int node = blockIdx.x * 4 + (threadIdx.x >> 6);
    int lane = threadIdx.x & 63;
    int half = lane >> 5;              // edge selector within pair
    int q    = lane & 31;              // chunk index within row
    unsigned s0 = rs[node], s1 = rs[node + 1];
    if (WIDTH == 128) {
        float4 acc = {0.f, 0.f, 0.f, 0.f};
        unsigned i = s0;
        for (; i + 8 <= s1; i += 8) {
            int e0 = es[i + half], e1 = es[i + 2 + half];
            int e2 = es[i + 4 + half], e3 = es[i + 6 + half];
            float4 v0 = *(const float4*)&h[(size_t)e0 * 128 + q * 4];
            float4 v1 = *(const float4*)&h[(size_t)e1 * 128 + q * 4];
            float4 v2 = *(const float4*)&h[(size_t)e2 * 128 + q * 4];
            float4 v3 = *(const float4*)&h[(size_t)e3 * 128 + q * 4];
            acc.x += (v0.x + v1.x) + (v2.x + v3.x);
            acc.y += (v0.y + v1.y) + (v2.y + v3.y);
            acc.z += (v0.z + v1.z) + (v2.z + v3.z);
            acc.w += (v0.w + v1.w) + (v2.w + v3.w);
        }
        for (; i + 2 <= s1; i += 2) {
            int e = es[i + half];
            float4 v = *(const float4*)&h[(size_t)e * 128 + q * 4];
            acc.x += v.x; acc.y += v.y; acc.z += v.z; acc.w += v.w;
        }
        if (i < s1 && half == 0) {     // odd leftover edge: half 0 only
            int e = es[i];
            float4 v = *(const float4*)&h[(size_t)e * 128 + q * 4];
            acc.x += v.x; acc.y += v.y; acc.z += v.z; acc.w += v.w;
        }
        acc.x += __shfl_xor(acc.x, 32, 64);
        acc.y += __shfl_xor(acc.y, 32, 64);
        acc.z += __shfl_xor(acc.z, 32, 64);
        acc.w += __shfl_xor(acc.w, 32, 64);
        if (half == 0) *(float4*)&agg[(size_t)node * 128 + q * 4] = acc;
    } else {
        float2 acc = {0.f, 0.f};
        unsigned i = s0;
        for (; i + 8 <= s1; i += 8) {
            int e0 = es[i + half], e1 = es[i + 2 + half];
            int e2 = es[i + 4 + half], e3 = es[i + 6 + half];
            float2 v0 = *(const float2*)&h[(size_t)e0 * 64 + q * 2];
            float2 v1 = *(const float2*)&h[(size_t)e1 * 64 + q * 2];
            float2 v2 = *(const float2*)&h[(size_t)e2 * 64 + q * 2];
            float2 v3 = *(const float2*)&h[(size_t)e3 * 64 + q * 2];
            acc.x += (v0.x + v1.x) + (v2.x + v3.x);
            acc.y += (v0.y + v1.y) + (v2.y + v3.y);
        }
        for (; i + 2 <= s1; i += 2) {
            int e = es[i + half];
            float2 v = *(const float2*)&h[(size_t)e * 64 + q * 2];
            acc.x += v.x; acc.y += v.y;
        }
        if (i < s1 && half == 0) {
            int e = es[i];
            float2 v = *(const float2*)&h[(size_t)e * 64 + q * 2];
            acc.x += v.x; acc.y += v.y;
        }
        acc.x += __shfl_xor(acc.x, 32, 64);
        acc.y += __shfl_xor(acc.y, 32, 64);
        if (half == 0) *(float2*)&agg[(size_t)node * 64 + q * 2] = acc;
    }
}

// C = epilogue(A @ W). 128 rows/block, 512 threads, thread = 4 rows x 4(+4) cols.
// MODE 0: C = ns[row]*relu(nd[row]*acc + b[col]); MODE 1: C = acc
template <int NCOL, int MODE>
__global__ __launch_bounds__(512)
void gemm_kernel(const float* __restrict__ A, const float* __restrict__ W,
                 const float* __restrict__ bias, const float* __restrict__ ns,
                 const float* __restrict__ nd, float* __restrict__ C) {
    __shared__ float Ws[128 * NCOL];
    __shared__ float As[128 * 130];
    int tid = threadIdx.x;
    int rowbase = blockIdx.x * 128;

    for (int i = tid; i < 128 * NCOL / 4; i += 512)
        *(float4*)&Ws[i * 4] = *(const float4*)&W[(size_t)i * 4];
    for (int i = tid; i < 128 * 32; i += 512) {
        int r = i >> 5, c4 = (i & 31) * 4;
        int row = rowbase + r;
        float4 v = {0.f, 0.f, 0.f, 0.f};
        if (row < N_NODES) v = *(const float4*)&A[(size_t)row * 128 + c4];
        *(float4*)&As[r * 130 + c4] = v;
    }
    __syncthreads();

    int cb = (tid & 15) * 4;
    int r0 = (tid >> 4) * 4;
    float4 acc[4][2];
    #pragma unroll
    for (int j = 0; j < 4; ++j) {
        acc[j][0] = make_float4(0.f, 0.f, 0.f, 0.f);
        acc[j][1] = make_float4(0.f, 0.f, 0.f, 0.f);
    }

    #pragma unroll 4
    for (int k = 0; k < 128; ++k) {
        float4 w0 = *(const float4*)&Ws[k * NCOL + cb];
        float4 w1;
        if (NCOL == 128) w1 = *(const float4*)&Ws[k * NCOL + cb + 64];
        #pragma unroll
        for (int j = 0; j < 4; ++j) {
            float a = As[(r0 + j) * 130 + k];
            acc[j][0].x += a * w0.x; acc[j][0].y += a * w0.y;
            acc[j][0].z += a * w0.z; acc[j][0].w += a * w0.w;
            if (NCOL == 128) {
                acc[j][1].x += a * w1.x; acc[j][1].y += a * w1.y;
                acc[j][1].z += a * w1.z; acc[j][1].w += a * w1.w;
            }
        }
    }

    #pragma unroll
    for (int j = 0; j < 4; ++j) {
        int row = rowbase + r0 + j;
        if (row >= N_NODES) break;
        if (MODE == 0) {
            float sd = nd[row], ss = ns[row];
            float4 o = acc[j][0];
            o.x = ss * fmaxf(sd * o.x + bias[cb + 0], 0.f);
            o.y = ss * fmaxf(sd * o.y + bias[cb + 1], 0.f);
            o.z = ss * fmaxf(sd * o.z + bias[cb + 2], 0.f);
            o.w = ss * fmaxf(sd * o.w + bias[cb + 3], 0.f);
            *(float4*)&C[(size_t)row * NCOL + cb] = o;
            if (NCOL == 128) {
                float4 p = acc[j][1];
                p.x = ss * fmaxf(sd * p.x + bias[cb + 64], 0.f);
                p.y = ss * fmaxf(sd * p.y + bias[cb + 65], 0.f);
                p.z = ss * fmaxf(sd * p.z + bias[cb + 66], 0.f);
                p.w = ss * fmaxf(sd * p.w + bias[cb + 67], 0.f);
                *(float4*)&C[(size_t)row * NCOL + cb + 64] = p;
            }
        } else {
            *(float4*)&C[(size_t)row * NCOL + cb] = acc[j][0];
            if (NCOL == 128) *(float4*)&C[(size_t)row * NCOL + cb + 64] = acc[j][1];
        }
    }
}

// fused heads: h4 = nd[n]*agg64[n] + b3;  PI[n] = h4.Wp + bp;  mN += h4
__global__ __launch_bounds__(256)
void head_kernel(const float* __restrict__ agg64, const float* __restrict__ nd,
                 const float* __restrict__ b3, const float* __restrict__ Wp,
                 const float* __restrict__ bp, float* __restrict__ out,
                 float* __restrict__ mN) {
    __shared__ float s[64];
    int lane = threadIdx.x & 63;
    int sub = threadIdx.x >> 6;
    if (threadIdx.x < 64) s[threadIdx.x] = 0.f;
    __syncthreads();
    float wp = Wp[lane];
    float bb = b3[lane];
    float bpv = bp[0];
    float msum = 0.f;
    for (int n = blockIdx.x * 4 + sub; n < N_NODES; n += gridDim.x * 4) {
        float h = nd[n] * agg64[(size_t)n * 64 + lane] + bb;
        msum += h;
        float p = h * wp;
        #pragma unroll
        for (int off = 32; off; off >>= 1) p += __shfl_down(p, off, 64);
        if (lane == 0) out[n] = p + bpv;
    }
    atomicAdd(&s[lane], msum);
    __syncthreads();
    if (threadIdx.x < 64) atomicAdd(&mN[threadIdx.x], s[threadIdx.x]);
}

__global__ void v_kernel(const float* __restrict__ mN, const float* __restrict__ Wv,
                         const float* __restrict__ bv, float* __restrict__ out) {
    int f = threadIdx.x;
    float v = mN[f] * Wv[f];
    #pragma unroll
    for (int off = 32; off; off >>= 1) v += __shfl_down(v, off, 64);
    if (f == 0) out[N_NODES] = v + bv[0];
}

extern "C" void kernel_launch(void* const* d_in, const int* in_sizes, int n_in,
                              void* d_out, int out_size, void* d_ws, size_t ws_size,
                              hipStream_t stream) {
    const float* feat = (const float*)d_in[0];
    const int*   src  = (const int*)d_in[1];
    const int*   dst  = (const int*)d_in[2];
    const float* W0 = (const float*)d_in[3];  const float* b0 = (const float*)d_in[4];
    const float* W1 = (const float*)d_in[5];  const float* b1 = (const float*)d_in[6];
    const float* W2 = (const float*)d_in[7];  const float* b2 = (const float*)d_in[8];
    const float* W3 = (const float*)d_in[9];  const float* b3 = (const float*)d_in[10];
    const float* Wp = (const float*)d_in[11]; const float* bp = (const float*)d_in[12];
    const float* Wv = (const float*)d_in[13]; const float* bv = (const float*)d_in[14];
    float* out = (float*)d_out;
    float* ws  = (float*)d_ws;

    float*    ns       = ws;
    float*    nd       = ws + 50000;
    unsigned* outd     = (unsigned*)(ws + 100000);
    unsigned* bsum     = (unsigned*)(ws + 100000);   // aliases outd (dead after norm)
    unsigned* ind      = (unsigned*)(ws + 150000);
    unsigned* rs       = (unsigned*)(ws + 200000);
    unsigned* cnt      = (unsigned*)(ws + 250004);
    float*    mN       = ws + 300004;
    int*      es       = (int*)(ws + 300080);
    float*    buf1     = ws + 1100080;
    float*    buf2     = ws + 7500080;
    float*    buf3     = ws + 13900080;

    hipMemsetAsync(ws + 100000, 0, 100000 * sizeof(float), stream);   // outd+ind
    hipMemsetAsync(mN, 0, 64 * sizeof(float), stream);

    deg_kernel<<<3125, 256, 0, stream>>>(src, dst, outd, ind);
    norm_kernel<<<196, 256, 0, stream>>>(outd, ind, ns, nd);
    scan1_kernel<<<196, 256, 0, stream>>>(ind, bsum);
    scan2_kernel<<<1, 256, 0, stream>>>(bsum, rs);
    scan3_kernel<<<196, 256, 0, stream>>>(ind, bsum, rs, cnt);
    fill_kernel<<<3125, 256, 0, stream>>>(src, dst, cnt, es);

    prescale_kernel<<<6250, 256, 0, stream>>>(feat, ns, buf1);        // hS = ns*feat

    // layer 0
    agg_kernel<128><<<12500, 256, 0, stream>>>(buf1, rs, es, buf2);
    gemm_kernel<128, 0><<<391, 512, 0, stream>>>(buf2, W0, b0, ns, nd, buf3);
    // layer 1
    agg_kernel<128><<<12500, 256, 0, stream>>>(buf3, rs, es, buf2);
    gemm_kernel<128, 0><<<391, 512, 0, stream>>>(buf2, W1, b1, ns, nd, buf1);
    // layer 2
    agg_kernel<128><<<12500, 256, 0, stream>>>(buf1, rs, es, buf2);
    gemm_kernel<128, 0><<<391, 512, 0, stream>>>(buf2, W2, b2, ns, nd, buf3);  // h3s
    // layer 3: transform FIRST (128->64), then aggregate 64-wide
    gemm_kernel<64, 1><<<391, 512, 0, stream>>>(buf3, W3, b3, ns, nd, buf1);
    agg_kernel<64><<<12500, 256, 0, stream>>>(buf1, rs, es, buf2);

    // heads
    head_kernel<<<196, 256, 0, stream>>>(buf2, nd, b3, Wp, bp, out, mN);
    v_kernel<<<1, 64, 0, stream>>>(mN, Wv, bv, out);
}

// Round 4
// 507.705 us; speedup vs baseline: 1.7214x; 1.2511x over previous
//
#include <hip/hip_runtime.h>
#include <cstddef>

#define N_NODES 50000
#define N_EDGES 800000
#define NB      391          // node-range buckets of 128 nodes
#define BCAP    3072         // slots per bucket (mean 2048, +22 sigma)
#define BPAD    16           // u32 stride between bucket counters (64B)

typedef unsigned u32;
typedef unsigned short u16;

__device__ __forceinline__ float bflo(u32 u) { return __uint_as_float(u << 16); }
__device__ __forceinline__ float bfhi(u32 u) { return __uint_as_float(u & 0xFFFF0000u); }
__device__ __forceinline__ u32 f2bf(float f) {            // RNE round to bf16 (as u16)
    u32 u = __float_as_uint(f);
    return (u + 0x7FFFu + ((u >> 16) & 1u)) >> 16;
}
__device__ __forceinline__ u32 packbf2(float a, float b) { return f2bf(a) | (f2bf(b) << 16); }

// ---------- byte offsets in workspace ----------
#define OFF_NS    0u          // f32[50000]
#define OFF_ND    200000u     // f32[50000]
#define OFF_IND   400000u     // u32[50000]
#define OFF_RS    600000u     // u32[50001]
#define OFF_ES    800016u     // int[800000]
#define OFF_DCNT  4000016u    // u32[NB*BPAD]        (zeroed)
#define OFF_SCNT  4025040u    // u32[NB*BPAD]        (zeroed; reused as bsum by scans)
#define OFF_MN    4050064u    // f32[64]             (zeroed)
#define OFF_DB    4050320u    // int2[NB*BCAP]
#define OFF_SB    13659536u   // int [NB*BCAP]
#define OFF_T0    18464144u   // bf16[50000*128]
#define OFF_T1    31264144u   // bf16[50000*128]
#define OFF_AGG   44064144u   // f32 [50000*128]  (also 64-wide f32 agg)
#define OFF_TT    69664144u   // bf16[50000*64]
#define ZERO_OFF  OFF_DCNT
#define ZERO_SZ   (OFF_DB - OFF_DCNT)   // 50304 B

// ---- pass1: bucket-append edges by dst (pairs) and by src (src only)
__global__ __launch_bounds__(256)
void pass1_kernel(const int* __restrict__ src, const int* __restrict__ dst,
                  u32* __restrict__ dcnt, u32* __restrict__ scnt,
                  int2* __restrict__ db, int* __restrict__ sb) {
    int e = blockIdx.x * 256 + threadIdx.x;
    if (e >= N_EDGES) return;
    int s = src[e], d = dst[e];
    u32 p = atomicAdd(&dcnt[(d >> 7) * BPAD], 1u);
    if (p < BCAP) db[(size_t)(d >> 7) * BCAP + p] = make_int2(s, d);
    u32 q = atomicAdd(&scnt[(s >> 7) * BPAD], 1u);
    if (q < BCAP) sb[(size_t)(s >> 7) * BCAP + q] = s;
}

// ---- per-bucket out-degree histogram -> ns
__global__ __launch_bounds__(256)
void shist_kernel(const int* __restrict__ sb, const u32* __restrict__ scnt,
                  float* __restrict__ ns) {
    __shared__ u32 h[128];
    int b = blockIdx.x, tid = threadIdx.x;
    if (tid < 128) h[tid] = 0;
    __syncthreads();
    u32 n = min(scnt[b * BPAD], (u32)BCAP);
    for (u32 i = tid; i < n; i += 256) atomicAdd(&h[sb[(size_t)b * BCAP + i] & 127], 1u);
    __syncthreads();
    if (tid < 128) {
        int node = b * 128 + tid;
        if (node < N_NODES) {
            u32 c = h[tid]; if (c < 1u) c = 1u;
            ns[node] = rsqrtf((float)c);
        }
    }
}

// ---- per-bucket in-degree histogram -> nd, ind
__global__ __launch_bounds__(256)
void dhist_kernel(const int2* __restrict__ db, const u32* __restrict__ dcnt,
                  float* __restrict__ nd, u32* __restrict__ ind) {
    __shared__ u32 h[128];
    int b = blockIdx.x, tid = threadIdx.x;
    if (tid < 128) h[tid] = 0;
    __syncthreads();
    u32 n = min(dcnt[b * BPAD], (u32)BCAP);
    for (u32 i = tid; i < n; i += 256) atomicAdd(&h[db[(size_t)b * BCAP + i].y & 127], 1u);
    __syncthreads();
    if (tid < 128) {
        int node = b * 128 + tid;
        if (node < N_NODES) {
            u32 c = h[tid];
            ind[node] = c;
            if (c < 1u) c = 1u;
            nd[node] = rsqrtf((float)c);
        }
    }
}

// ---- hierarchical scan of ind -> rs
__global__ __launch_bounds__(256)
void scan1_kernel(const u32* __restrict__ deg, u32* __restrict__ bsum) {
    __shared__ u32 s[4];
    int i = blockIdx.x * 256 + threadIdx.x;
    u32 v = (i < N_NODES) ? deg[i] : 0u;
    #pragma unroll
    for (int off = 32; off; off >>= 1) v += __shfl_down(v, off, 64);
    if ((threadIdx.x & 63) == 0) s[threadIdx.x >> 6] = v;
    __syncthreads();
    if (threadIdx.x == 0) bsum[blockIdx.x] = s[0] + s[1] + s[2] + s[3];
}

__global__ __launch_bounds__(256)
void scan2_kernel(u32* __restrict__ bsum, u32* __restrict__ rs) {
    __shared__ u32 sb_[256];
    int tid = threadIdx.x;
    u32 v = (tid < 196) ? bsum[tid] : 0u;
    sb_[tid] = v;
    __syncthreads();
    for (int off = 1; off < 256; off <<= 1) {
        u32 t = (tid >= off) ? sb_[tid - off] : 0u;
        __syncthreads();
        sb_[tid] += t;
        __syncthreads();
    }
    if (tid < 196) bsum[tid] = sb_[tid] - v;
    if (tid == 0) rs[N_NODES] = N_EDGES;
}

__global__ __launch_bounds__(256)
void scan3_kernel(const u32* __restrict__ deg, const u32* __restrict__ bsum,
                  u32* __restrict__ rs) {
    __shared__ u32 sb_[256];
    int tid = threadIdx.x;
    int i = blockIdx.x * 256 + tid;
    u32 v = (i < N_NODES) ? deg[i] : 0u;
    sb_[tid] = v;
    __syncthreads();
    for (int off = 1; off < 256; off <<= 1) {
        u32 t = (tid >= off) ? sb_[tid - off] : 0u;
        __syncthreads();
        sb_[tid] += t;
        __syncthreads();
    }
    if (i < N_NODES) rs[i] = bsum[blockIdx.x] + sb_[tid] - v;
}

// ---- place edges into CSR (per-bucket LDS offsets; dense 12KB write window)
__global__ __launch_bounds__(256)
void place_kernel(const int2* __restrict__ db, const u32* __restrict__ dcnt,
                  const u32* __restrict__ rs, int* __restrict__ es) {
    __shared__ u32 off[128];
    __shared__ u32 rbase[128];
    int b = blockIdx.x, tid = threadIdx.x;
    if (tid < 128) {
        off[tid] = 0;
        int node = b * 128 + tid;
        rbase[tid] = (node < N_NODES) ? rs[node] : 0u;
    }
    __syncthreads();
    u32 n = min(dcnt[b * BPAD], (u32)BCAP);
    for (u32 i = tid; i < n; i += 256) {
        int2 p = db[(size_t)b * BCAP + i];
        u32 loc = (u32)p.y & 127u;
        u32 pos = rbase[loc] + atomicAdd(&off[loc], 1u);
        es[pos] = p.x;
    }
}

// ---- hS(bf16) = feat * ns[row]
__global__ __launch_bounds__(256)
void prescale_kernel(const float* __restrict__ feat, const float* __restrict__ ns,
                     u16* __restrict__ hS) {
    int i = blockIdx.x * 256 + threadIdx.x;      // over N_NODES*32 float4 chunks
    if (i < N_NODES * 32) {
        float s = ns[i >> 5];
        float4 v = *(const float4*)&feat[(size_t)i * 4];
        uint2 o;
        o.x = packbf2(s * v.x, s * v.y);
        o.y = packbf2(s * v.z, s * v.w);
        *(uint2*)&hS[(size_t)i * 4] = o;
    }
}

// ---- 128-wide bf16 gather-aggregate: 1 wave/node, half-wave = 1 row, f32 out
__global__ __launch_bounds__(256)
void agg128_kernel(const u16* __restrict__ h, const u32* __restrict__ rs,
                   const int* __restrict__ es, float* __restrict__ agg) {
    int node = blockIdx.x * 4 + (threadIdx.x >> 6);
    int lane = threadIdx.x & 63;
    int half = lane >> 5;
    int q    = lane & 31;                 // uint2 chunk (4 bf16) within row
    const uint2* hp = (const uint2*)h;    // row = 32 uint2
    u32 s0 = rs[node], s1 = rs[node + 1];
    float4 acc = {0.f, 0.f, 0.f, 0.f};
    u32 i = s0;
    for (; i + 8 <= s1; i += 8) {
        int e0 = es[i + half],     e1 = es[i + 2 + half];
        int e2 = es[i + 4 + half], e3 = es[i + 6 + half];
        uint2 a = hp[(size_t)e0 * 32 + q];
        uint2 b = hp[(size_t)e1 * 32 + q];
        uint2 c = hp[(size_t)e2 * 32 + q];
        uint2 d = hp[(size_t)e3 * 32 + q];
        acc.x += (bflo(a.x) + bflo(b.x)) + (bflo(c.x) + bflo(d.x));
        acc.y += (bfhi(a.x) + bfhi(b.x)) + (bfhi(c.x) + bfhi(d.x));
        acc.z += (bflo(a.y) + bflo(b.y)) + (bflo(c.y) + bflo(d.y));
        acc.w += (bfhi(a.y) + bfhi(b.y)) + (bfhi(c.y) + bfhi(d.y));
    }
    for (; i + 2 <= s1; i += 2) {
        int e = es[i + half];
        uint2 a = hp[(size_t)e * 32 + q];
        acc.x += bflo(a.x); acc.y += bfhi(a.x);
        acc.z += bflo(a.y); acc.w += bfhi(a.y);
    }
    if (i < s1 && half == 0) {
        int e = es[i];
        uint2 a = hp[(size_t)e * 32 + q];
        acc.x += bflo(a.x); acc.y += bfhi(a.x);
        acc.z += bflo(a.y); acc.w += bfhi(a.y);
    }
    acc.x += __shfl_xor(acc.x, 32, 64);
    acc.y += __shfl_xor(acc.y, 32, 64);
    acc.z += __shfl_xor(acc.z, 32, 64);
    acc.w += __shfl_xor(acc.w, 32, 64);
    if (half == 0) *(float4*)&agg[(size_t)node * 128 + q * 4] = acc;
}

// ---- 64-wide bf16 gather-aggregate: quarter-wave = 1 row (4 edges/pass), f32 out
__global__ __launch_bounds__(256)
void agg64_kernel(const u16* __restrict__ h, const u32* __restrict__ rs,
                  const int* __restrict__ es, float* __restrict__ agg) {
    int node = blockIdx.x * 4 + (threadIdx.x >> 6);
    int lane = threadIdx.x & 63;
    int quarter = lane >> 4;
    int q = lane & 15;                    // uint2 chunk within 64-wide row
    const uint2* hp = (const uint2*)h;    // row = 16 uint2
    u32 s0 = rs[node], s1 = rs[node + 1];
    float4 acc = {0.f, 0.f, 0.f, 0.f};
    u32 i = s0;
    for (; i + 8 <= s1; i += 8) {
        int e0 = es[i + quarter], e1 = es[i + 4 + quarter];
        uint2 a = hp[(size_t)e0 * 16 + q];
        uint2 b = hp[(size_t)e1 * 16 + q];
        acc.x += bflo(a.x) + bflo(b.x);
        acc.y += bfhi(a.x) + bfhi(b.x);
        acc.z += bflo(a.y) + bflo(b.y);
        acc.w += bfhi(a.y) + bfhi(b.y);
    }
    for (; i + 4 <= s1; i += 4) {
        int e = es[i + quarter];
        uint2 a = hp[(size_t)e * 16 + q];
        acc.x += bflo(a.x); acc.y += bfhi(a.x);
        acc.z += bflo(a.y); acc.w += bfhi(a.y);
    }
    u32 rem = s1 - i;
    if ((u32)quarter < rem) {
        int e = es[i + quarter];
        uint2 a = hp[(size_t)e * 16 + q];
        acc.x += bflo(a.x); acc.y += bfhi(a.x);
        acc.z += bflo(a.y); acc.w += bfhi(a.y);
    }
    acc.x += __shfl_xor(acc.x, 16, 64); acc.x += __shfl_xor(acc.x, 32, 64);
    acc.y += __shfl_xor(acc.y, 16, 64); acc.y += __shfl_xor(acc.y, 32, 64);
    acc.z += __shfl_xor(acc.z, 16, 64); acc.z += __shfl_xor(acc.z, 32, 64);
    acc.w += __shfl_xor(acc.w, 16, 64); acc.w += __shfl_xor(acc.w, 32, 64);
    if (lane < 16) *(float4*)&agg[(size_t)node * 64 + q * 4] = acc;
}

// ---- GEMM: 128 rows/block, 512 thr, thread = 4 rows x 4(+4) cols; bf16 OUT.
// MODE 0: C = ns*relu(nd*acc + b); MODE 1: C = acc. ABF16: A is bf16 table.
template <int NCOL, int MODE, bool ABF16>
__global__ __launch_bounds__(512)
void gemm_kernel(const void* __restrict__ Av, const float* __restrict__ W,
                 const float* __restrict__ bias, const float* __restrict__ ns,
                 const float* __restrict__ nd, u16* __restrict__ C) {
    __shared__ float Ws[128 * NCOL];
    __shared__ float As[128 * 130];
    int tid = threadIdx.x;
    int rowbase = blockIdx.x * 128;

    for (int i = tid; i < 128 * NCOL / 4; i += 512)
        *(float4*)&Ws[i * 4] = *(const float4*)&W[(size_t)i * 4];
    if (ABF16) {
        const uint4* A = (const uint4*)Av;            // 8 bf16 per uint4
        for (int i = tid; i < 128 * 16; i += 512) {
            int r = i >> 4, c8 = (i & 15) * 8;
            int row = rowbase + r;
            uint4 v = {0u, 0u, 0u, 0u};
            if (row < N_NODES) v = A[(size_t)row * 16 + (i & 15)];
            float4 f0 = {bflo(v.x), bfhi(v.x), bflo(v.y), bfhi(v.y)};
            float4 f1 = {bflo(v.z), bfhi(v.z), bflo(v.w), bfhi(v.w)};
            *(float4*)&As[r * 130 + c8]     = f0;
            *(float4*)&As[r * 130 + c8 + 4] = f1;
        }
    } else {
        const float* A = (const float*)Av;
        for (int i = tid; i < 128 * 32; i += 512) {
            int r = i >> 5, c4 = (i & 31) * 4;
            int row = rowbase + r;
            float4 v = {0.f, 0.f, 0.f, 0.f};
            if (row < N_NODES) v = *(const float4*)&A[(size_t)row * 128 + c4];
            *(float4*)&As[r * 130 + c4] = v;
        }
    }
    __syncthreads();

    int cb = (tid & 15) * 4;
    int r0 = (tid >> 4) * 4;
    float4 acc[4][2];
    #pragma unroll
    for (int j = 0; j < 4; ++j) {
        acc[j][0] = make_float4(0.f, 0.f, 0.f, 0.f);
        acc[j][1] = make_float4(0.f, 0.f, 0.f, 0.f);
    }

    #pragma unroll 4
    for (int k = 0; k < 128; ++k) {
        float4 w0 = *(const float4*)&Ws[k * NCOL + cb];
        float4 w1;
        if (NCOL == 128) w1 = *(const float4*)&Ws[k * NCOL + cb + 64];
        #pragma unroll
        for (int j = 0; j < 4; ++j) {
            float a = As[(r0 + j) * 130 + k];
            acc[j][0].x += a * w0.x; acc[j][0].y += a * w0.y;
            acc[j][0].z += a * w0.z; acc[j][0].w += a * w0.w;
            if (NCOL == 128) {
                acc[j][1].x += a * w1.x; acc[j][1].y += a * w1.y;
                acc[j][1].z += a * w1.z; acc[j][1].w += a * w1.w;
            }
        }
    }

    #pragma unroll
    for (int j = 0; j < 4; ++j) {
        int row = rowbase + r0 + j;
        if (row >= N_NODES) break;
        if (MODE == 0) {
            float sd = nd[row], ss = ns[row];
            float4 o = acc[j][0];
            o.x = ss * fmaxf(sd * o.x + bias[cb + 0], 0.f);
            o.y = ss * fmaxf(sd * o.y + bias[cb + 1], 0.f);
            o.z = ss * fmaxf(sd * o.z + bias[cb + 2], 0.f);
            o.w = ss * fmaxf(sd * o.w + bias[cb + 3], 0.f);
            uint2 pk = {packbf2(o.x, o.y), packbf2(o.z, o.w)};
            *(uint2*)&C[(size_t)row * NCOL + cb] = pk;
            if (NCOL == 128) {
                float4 p = acc[j][1];
                p.x = ss * fmaxf(sd * p.x + bias[cb + 64], 0.f);
                p.y = ss * fmaxf(sd * p.y + bias[cb + 65], 0.f);
                p.z = ss * fmaxf(sd * p.z + bias[cb + 66], 0.f);
                p.w = ss * fmaxf(sd * p.w + bias[cb + 67], 0.f);
                uint2 pk2 = {packbf2(p.x, p.y), packbf2(p.z, p.w)};
                *(uint2*)&C[(size_t)row * NCOL + cb + 64] = pk2;
            }
        } else {
            float4 o = acc[j][0];
            uint2 pk = {packbf2(o.x, o.y), packbf2(o.z, o.w)};
            *(uint2*)&C[(size_t)row * NCOL + cb] = pk;
            if (NCOL == 128) {
                float4 p = acc[j][1];
                uint2 pk2 = {packbf2(p.x, p.y), packbf2(p.z, p.w)};
                *(uint2*)&C[(size_t)row * NCOL + cb + 64] = pk2;
            }
        }
    }
}

// ---- fused heads: h4 = nd*agg64 + b3;  PI = h4.Wp + bp;  mN += h4
__global__ __launch_bounds__(256)
void head_kernel(const float* __restrict__ agg64, const float* __restrict__ nd,
                 const float* __restrict__ b3, const float* __restrict__ Wp,
                 const float* __restrict__ bp, float* __restrict__ out,
                 float* __restrict__ mN) {
    __shared__ float s[64];
    int lane = threadIdx.x & 63;
    int sub = threadIdx.x >> 6;
    if (threadIdx.x < 64) s[threadIdx.x] = 0.f;
    __syncthreads();
    float wp = Wp[lane];
    float bb = b3[lane];
    float bpv = bp[0];
    float msum = 0.f;
    for (int n = blockIdx.x * 4 + sub; n < N_NODES; n += gridDim.x * 4) {
        float h = nd[n] * agg64[(size_t)n * 64 + lane] + bb;
        msum += h;
        float p = h * wp;
        #pragma unroll
        for (int off = 32; off; off >>= 1) p += __shfl_down(p, off, 64);
        if (lane == 0) out[n] = p + bpv;
    }
    atomicAdd(&s[lane], msum);
    __syncthreads();
    if (threadIdx.x < 64) atomicAdd(&mN[threadIdx.x], s[threadIdx.x]);
}

__global__ void v_kernel(const float* __restrict__ mN, const float* __restrict__ Wv,
                         const float* __restrict__ bv, float* __restrict__ out) {
    int f = threadIdx.x;
    float v = mN[f] * Wv[f];
    #pragma unroll
    for (int off = 32; off; off >>= 1) v += __shfl_down(v, off, 64);
    if (f == 0) out[N_NODES] = v + bv[0];
}

extern "C" void kernel_launch(void* const* d_in, const int* in_sizes, int n_in,
                              void* d_out, int out_size, void* d_ws, size_t ws_size,
                              hipStream_t stream) {
    const float* feat = (const float*)d_in[0];
    const int*   src  = (const int*)d_in[1];
    const int*   dst  = (const int*)d_in[2];
    const float* W0 = (const float*)d_in[3];  const float* b0 = (const float*)d_in[4];
    const float* W1 = (const float*)d_in[5];  const float* b1 = (const float*)d_in[6];
    const float* W2 = (const float*)d_in[7];  const float* b2 = (const float*)d_in[8];
    const float* W3 = (const float*)d_in[9];  const float* b3 = (const float*)d_in[10];
    const float* Wp = (const float*)d_in[11]; const float* bp = (const float*)d_in[12];
    const float* Wv = (const float*)d_in[13]; const float* bv = (const float*)d_in[14];
    float* out = (float*)d_out;
    char*  wsb = (char*)d_ws;

    float* ns   = (float*)(wsb + OFF_NS);
    float* nd   = (float*)(wsb + OFF_ND);
    u32*   ind  = (u32*)(wsb + OFF_IND);
    u32*   rs   = (u32*)(wsb + OFF_RS);
    int*   es   = (int*)(wsb + OFF_ES);
    u32*   dcnt = (u32*)(wsb + OFF_DCNT);
    u32*   scnt = (u32*)(wsb + OFF_SCNT);   // also bsum for scans (dead after shist)
    float* mN   = (float*)(wsb + OFF_MN);
    int2*  db   = (int2*)(wsb + OFF_DB);
    int*   sb   = (int*)(wsb + OFF_SB);
    u16*   T0   = (u16*)(wsb + OFF_T0);
    u16*   T1   = (u16*)(wsb + OFF_T1);
    float* AGG  = (float*)(wsb + OFF_AGG);
    u16*   Tt   = (u16*)(wsb + OFF_TT);

    hipMemsetAsync(wsb + ZERO_OFF, 0, ZERO_SZ, stream);   // dcnt, scnt, mN

    pass1_kernel<<<3125, 256, 0, stream>>>(src, dst, dcnt, scnt, db, sb);
    shist_kernel<<<NB, 256, 0, stream>>>(sb, scnt, ns);
    dhist_kernel<<<NB, 256, 0, stream>>>(db, dcnt, nd, ind);
    scan1_kernel<<<196, 256, 0, stream>>>(ind, scnt);
    scan2_kernel<<<1, 256, 0, stream>>>(scnt, rs);
    scan3_kernel<<<196, 256, 0, stream>>>(ind, scnt, rs);
    place_kernel<<<NB, 256, 0, stream>>>(db, dcnt, rs, es);

    prescale_kernel<<<6250, 256, 0, stream>>>(feat, ns, T0);

    // layer 0
    agg128_kernel<<<12500, 256, 0, stream>>>(T0, rs, es, AGG);
    gemm_kernel<128, 0, false><<<391, 512, 0, stream>>>(AGG, W0, b0, ns, nd, T1);
    // layer 1
    agg128_kernel<<<12500, 256, 0, stream>>>(T1, rs, es, AGG);
    gemm_kernel<128, 0, false><<<391, 512, 0, stream>>>(AGG, W1, b1, ns, nd, T0);
    // layer 2
    agg128_kernel<<<12500, 256, 0, stream>>>(T0, rs, es, AGG);
    gemm_kernel<128, 0, false><<<391, 512, 0, stream>>>(AGG, W2, b2, ns, nd, T1);  // h3s
    // layer 3: transform first (128->64, bf16 in), then aggregate 64-wide
    gemm_kernel<64, 1, true><<<391, 512, 0, stream>>>(T1, W3, b3, ns, nd, Tt);
    agg64_kernel<<<12500, 256, 0, stream>>>(Tt, rs, es, AGG);

    // heads
    head_kernel<<<196, 256, 0, stream>>>(AGG, nd, b3, Wp, bp, out, mN);
    v_kernel<<<1, 64, 0, stream>>>(mN, Wv, bv, out);
}

// Round 5
// 435.596 us; speedup vs baseline: 2.0063x; 1.1655x over previous
//
#include <hip/hip_runtime.h>
#include <cstddef>

#define N_NODES 50000
#define N_EDGES 800000
#define NBUK    196        // dst/src buckets of 256 nodes
#define NBLK    256        // edge-slice blocks
#define EPB     3125       // edges per slice block (256*3125 = 800000)

typedef unsigned u32;
typedef unsigned short u16;

__device__ __forceinline__ float bflo(u32 u) { return __uint_as_float(u << 16); }
__device__ __forceinline__ float bfhi(u32 u) { return __uint_as_float(u & 0xFFFF0000u); }
__device__ __forceinline__ u32 f2bf(float f) {            // RNE round to bf16
    u32 u = __float_as_uint(f);
    return (u + 0x7FFFu + ((u >> 16) & 1u)) >> 16;
}
__device__ __forceinline__ u32 packbf2(float a, float b) { return f2bf(a) | (f2bf(b) << 16); }

// ---------- byte offsets in workspace ----------
#define OFF_NS    0u          // f32[50000]
#define OFF_ND    200000u     // f32[50000]
#define OFF_RS    400000u     // u32[50001]
#define OFF_ES    600016u     // int[800000]
#define OFF_CNTD  3800016u    // u32[NBLK*NBUK]
#define OFF_CNTS  4000720u    // u32[NBLK*NBUK]
#define OFF_TOTD  4201424u    // u32[NBUK]
#define OFF_TOTS  4202208u    // u32[NBUK]
#define OFF_BASED 4202992u    // u32[NBUK]
#define OFF_BASES 4203776u    // u32[NBUK]
#define OFF_MN    4204560u    // f32[64*16] line-padded accumulators (zeroed)
#define OFF_DB    4208656u    // int2[800000]
#define OFF_SB    10608656u   // int [800000]
#define OFF_T0    13808656u   // bf16[50000*128]
#define OFF_T1    26608656u   // bf16[50000*128]
#define OFF_TA    39408656u   // bf16[50000*128]  (agg output)
#define OFF_TT    52208656u   // bf16[50000*64]
// end 58608656 B

// ---- phase 1: per-slice bucket counts (LDS histogram, no global atomics)
__global__ __launch_bounds__(256)
void p1_kernel(const int* __restrict__ src, const int* __restrict__ dst,
               u32* __restrict__ cntD, u32* __restrict__ cntS) {
    __shared__ u32 dc[NBUK], sc[NBUK];
    int b = blockIdx.x, tid = threadIdx.x;
    if (tid < NBUK) { dc[tid] = 0; sc[tid] = 0; }
    __syncthreads();
    int lo = b * EPB, hi = lo + EPB;
    for (int e = lo + tid; e < hi; e += 256) {
        atomicAdd(&dc[dst[e] >> 8], 1u);
        atomicAdd(&sc[src[e] >> 8], 1u);
    }
    __syncthreads();
    if (tid < NBUK) {
        cntD[b * NBUK + tid] = dc[tid];
        cntS[b * NBUK + tid] = sc[tid];
    }
}

// ---- phase 2a: per-bucket scan over the 256 slice counts (in place -> exclusive)
__global__ __launch_bounds__(256)
void p2a_kernel(u32* __restrict__ cntD, u32* __restrict__ cntS,
                u32* __restrict__ totD, u32* __restrict__ totS) {
    __shared__ u32 sc[256];
    int k = blockIdx.x, tid = threadIdx.x;
    u32 v = cntD[tid * NBUK + k];
    sc[tid] = v;
    __syncthreads();
    for (int o = 1; o < 256; o <<= 1) {
        u32 t = (tid >= o) ? sc[tid - o] : 0u;
        __syncthreads(); sc[tid] += t; __syncthreads();
    }
    cntD[tid * NBUK + k] = sc[tid] - v;
    if (tid == 255) totD[k] = sc[255];
    __syncthreads();
    v = cntS[tid * NBUK + k];
    sc[tid] = v;
    __syncthreads();
    for (int o = 1; o < 256; o <<= 1) {
        u32 t = (tid >= o) ? sc[tid - o] : 0u;
        __syncthreads(); sc[tid] += t; __syncthreads();
    }
    cntS[tid * NBUK + k] = sc[tid] - v;
    if (tid == 255) totS[k] = sc[255];
}

// ---- phase 2b: bucket base offsets
__global__ __launch_bounds__(256)
void p2b_kernel(const u32* __restrict__ totD, const u32* __restrict__ totS,
                u32* __restrict__ baseD, u32* __restrict__ baseS, u32* __restrict__ rs) {
    __shared__ u32 sc[256];
    int tid = threadIdx.x;
    u32 v = (tid < NBUK) ? totD[tid] : 0u;
    sc[tid] = v;
    __syncthreads();
    for (int o = 1; o < 256; o <<= 1) {
        u32 t = (tid >= o) ? sc[tid - o] : 0u;
        __syncthreads(); sc[tid] += t; __syncthreads();
    }
    if (tid < NBUK) baseD[tid] = sc[tid] - v;
    __syncthreads();
    v = (tid < NBUK) ? totS[tid] : 0u;
    sc[tid] = v;
    __syncthreads();
    for (int o = 1; o < 256; o <<= 1) {
        u32 t = (tid >= o) ? sc[tid - o] : 0u;
        __syncthreads(); sc[tid] += t; __syncthreads();
    }
    if (tid < NBUK) baseS[tid] = sc[tid] - v;
    if (tid == 0) rs[N_NODES] = N_EDGES;
}

// ---- phase 3: place edges into bucket runs (contiguous per (block,bucket))
__global__ __launch_bounds__(256)
void p3_kernel(const int* __restrict__ src, const int* __restrict__ dst,
               const u32* __restrict__ cntD, const u32* __restrict__ cntS,
               const u32* __restrict__ baseD, const u32* __restrict__ baseS,
               int2* __restrict__ db, int* __restrict__ sb) {
    __shared__ u32 od[NBUK], os[NBUK];
    int b = blockIdx.x, tid = threadIdx.x;
    if (tid < NBUK) {
        od[tid] = baseD[tid] + cntD[b * NBUK + tid];
        os[tid] = baseS[tid] + cntS[b * NBUK + tid];
    }
    __syncthreads();
    int lo = b * EPB, hi = lo + EPB;
    for (int e = lo + tid; e < hi; e += 256) {
        int s = src[e], d = dst[e];
        u32 p = atomicAdd(&od[d >> 8], 1u);
        db[p] = make_int2(s, d);
        u32 q = atomicAdd(&os[s >> 8], 1u);
        sb[q] = s;
    }
}

// ---- phase 4d: per-bucket CSR finalize (in-deg -> nd, rs, es placement)
__global__ __launch_bounds__(256)
void p4d_kernel(const int2* __restrict__ db, const u32* __restrict__ totD,
                const u32* __restrict__ baseD, float* __restrict__ nd,
                u32* __restrict__ rs, int* __restrict__ es) {
    __shared__ u32 hist[256], sc[256], off[256];
    int k = blockIdx.x, tid = threadIdx.x;
    hist[tid] = 0;
    __syncthreads();
    u32 nEd = totD[k], base = baseD[k];
    for (u32 i = tid; i < nEd; i += 256)
        atomicAdd(&hist[db[base + i].y & 255], 1u);
    __syncthreads();
    u32 v = hist[tid];
    sc[tid] = v;
    __syncthreads();
    for (int o = 1; o < 256; o <<= 1) {
        u32 t = (tid >= o) ? sc[tid - o] : 0u;
        __syncthreads(); sc[tid] += t; __syncthreads();
    }
    u32 pf = sc[tid] - v;
    int node = k * 256 + tid;
    if (node < N_NODES) {
        rs[node] = base + pf;
        u32 c = v < 1u ? 1u : v;
        nd[node] = rsqrtf((float)c);
    }
    off[tid] = base + pf;
    __syncthreads();
    for (u32 i = tid; i < nEd; i += 256) {
        int2 p = db[base + i];
        u32 pos = atomicAdd(&off[p.y & 255], 1u);
        es[pos] = p.x;
    }
}

// ---- phase 4s: per-bucket out-degree -> ns
__global__ __launch_bounds__(256)
void p4s_kernel(const int* __restrict__ sb, const u32* __restrict__ totS,
                const u32* __restrict__ baseS, float* __restrict__ ns) {
    __shared__ u32 hist[256];
    int k = blockIdx.x, tid = threadIdx.x;
    hist[tid] = 0;
    __syncthreads();
    u32 n = totS[k], base = baseS[k];
    for (u32 i = tid; i < n; i += 256)
        atomicAdd(&hist[sb[base + i] & 255], 1u);
    __syncthreads();
    int node = k * 256 + tid;
    if (node < N_NODES) {
        u32 c = hist[tid]; if (c < 1u) c = 1u;
        ns[node] = rsqrtf((float)c);
    }
}

// ---- hS(bf16) = feat * ns[row]
__global__ __launch_bounds__(256)
void prescale_kernel(const float* __restrict__ feat, const float* __restrict__ ns,
                     u16* __restrict__ hS) {
    int i = blockIdx.x * 256 + threadIdx.x;      // over N_NODES*32 float4 chunks
    if (i < N_NODES * 32) {
        float s = ns[i >> 5];
        float4 v = *(const float4*)&feat[(size_t)i * 4];
        uint2 o;
        o.x = packbf2(s * v.x, s * v.y);
        o.y = packbf2(s * v.z, s * v.w);
        *(uint2*)&hS[(size_t)i * 4] = o;
    }
}

// ---- 128-wide bf16 gather-aggregate, bf16 out; 1 wave/node, half-wave = 1 row
__global__ __launch_bounds__(256)
void agg128_kernel(const u16* __restrict__ h, const u32* __restrict__ rs,
                   const int* __restrict__ es, u16* __restrict__ agg) {
    int node = blockIdx.x * 4 + (threadIdx.x >> 6);
    int lane = threadIdx.x & 63;
    int half = lane >> 5;
    int q    = lane & 31;                 // uint2 chunk (4 bf16) within row
    const uint2* hp = (const uint2*)h;    // row = 32 uint2
    u32 s0 = rs[node], s1 = rs[node + 1];
    float4 acc = {0.f, 0.f, 0.f, 0.f};
    u32 i = s0;
    for (; i + 8 <= s1; i += 8) {
        int e0 = es[i + half],     e1 = es[i + 2 + half];
        int e2 = es[i + 4 + half], e3 = es[i + 6 + half];
        uint2 a = hp[(size_t)e0 * 32 + q];
        uint2 b = hp[(size_t)e1 * 32 + q];
        uint2 c = hp[(size_t)e2 * 32 + q];
        uint2 d = hp[(size_t)e3 * 32 + q];
        acc.x += (bflo(a.x) + bflo(b.x)) + (bflo(c.x) + bflo(d.x));
        acc.y += (bfhi(a.x) + bfhi(b.x)) + (bfhi(c.x) + bfhi(d.x));
        acc.z += (bflo(a.y) + bflo(b.y)) + (bflo(c.y) + bflo(d.y));
        acc.w += (bfhi(a.y) + bfhi(b.y)) + (bfhi(c.y) + bfhi(d.y));
    }
    for (; i + 2 <= s1; i += 2) {
        int e = es[i + half];
        uint2 a = hp[(size_t)e * 32 + q];
        acc.x += bflo(a.x); acc.y += bfhi(a.x);
        acc.z += bflo(a.y); acc.w += bfhi(a.y);
    }
    if (i < s1 && half == 0) {
        int e = es[i];
        uint2 a = hp[(size_t)e * 32 + q];
        acc.x += bflo(a.x); acc.y += bfhi(a.x);
        acc.z += bflo(a.y); acc.w += bfhi(a.y);
    }
    acc.x += __shfl_xor(acc.x, 32, 64);
    acc.y += __shfl_xor(acc.y, 32, 64);
    acc.z += __shfl_xor(acc.z, 32, 64);
    acc.w += __shfl_xor(acc.w, 32, 64);
    if (half == 0) {
        uint2 pk = {packbf2(acc.x, acc.y), packbf2(acc.z, acc.w)};
        *(uint2*)&agg[(size_t)node * 128 + q * 4] = pk;
    }
}

// ---- GEMM: A bf16, W f32 (LDS), 128 rows/block, 512 thr; bf16 out.
// MODE 0: C = ns*relu(nd*acc + b); MODE 1: C = acc
template <int NCOL, int MODE>
__global__ __launch_bounds__(512)
void gemm_kernel(const u16* __restrict__ Ab, const float* __restrict__ W,
                 const float* __restrict__ bias, const float* __restrict__ ns,
                 const float* __restrict__ nd, u16* __restrict__ C) {
    __shared__ float Ws[128 * NCOL];
    __shared__ float As[128 * 130];
    int tid = threadIdx.x;
    int rowbase = blockIdx.x * 128;

    for (int i = tid; i < 128 * NCOL / 4; i += 512)
        *(float4*)&Ws[i * 4] = *(const float4*)&W[(size_t)i * 4];
    {
        const uint4* A = (const uint4*)Ab;            // 8 bf16 per uint4
        for (int i = tid; i < 128 * 16; i += 512) {
            int r = i >> 4, c8 = (i & 15) * 8;
            int row = rowbase + r;
            uint4 v = {0u, 0u, 0u, 0u};
            if (row < N_NODES) v = A[(size_t)row * 16 + (i & 15)];
            float4 f0 = {bflo(v.x), bfhi(v.x), bflo(v.y), bfhi(v.y)};
            float4 f1 = {bflo(v.z), bfhi(v.z), bflo(v.w), bfhi(v.w)};
            *(float4*)&As[r * 130 + c8]     = f0;
            *(float4*)&As[r * 130 + c8 + 4] = f1;
        }
    }
    __syncthreads();

    int cb = (tid & 15) * 4;
    int r0 = (tid >> 4) * 4;
    float4 acc[4][2];
    #pragma unroll
    for (int j = 0; j < 4; ++j) {
        acc[j][0] = make_float4(0.f, 0.f, 0.f, 0.f);
        acc[j][1] = make_float4(0.f, 0.f, 0.f, 0.f);
    }

    #pragma unroll 4
    for (int k = 0; k < 128; ++k) {
        float4 w0 = *(const float4*)&Ws[k * NCOL + cb];
        float4 w1;
        if (NCOL == 128) w1 = *(const float4*)&Ws[k * NCOL + cb + 64];
        #pragma unroll
        for (int j = 0; j < 4; ++j) {
            float a = As[(r0 + j) * 130 + k];
            acc[j][0].x += a * w0.x; acc[j][0].y += a * w0.y;
            acc[j][0].z += a * w0.z; acc[j][0].w += a * w0.w;
            if (NCOL == 128) {
                acc[j][1].x += a * w1.x; acc[j][1].y += a * w1.y;
                acc[j][1].z += a * w1.z; acc[j][1].w += a * w1.w;
            }
        }
    }

    #pragma unroll
    for (int j = 0; j < 4; ++j) {
        int row = rowbase + r0 + j;
        if (row >= N_NODES) break;
        if (MODE == 0) {
            float sd = nd[row], ss = ns[row];
            float4 o = acc[j][0];
            o.x = ss * fmaxf(sd * o.x + bias[cb + 0], 0.f);
            o.y = ss * fmaxf(sd * o.y + bias[cb + 1], 0.f);
            o.z = ss * fmaxf(sd * o.z + bias[cb + 2], 0.f);
            o.w = ss * fmaxf(sd * o.w + bias[cb + 3], 0.f);
            uint2 pk = {packbf2(o.x, o.y), packbf2(o.z, o.w)};
            *(uint2*)&C[(size_t)row * NCOL + cb] = pk;
            if (NCOL == 128) {
                float4 p = acc[j][1];
                p.x = ss * fmaxf(sd * p.x + bias[cb + 64], 0.f);
                p.y = ss * fmaxf(sd * p.y + bias[cb + 65], 0.f);
                p.z = ss * fmaxf(sd * p.z + bias[cb + 66], 0.f);
                p.w = ss * fmaxf(sd * p.w + bias[cb + 67], 0.f);
                uint2 pk2 = {packbf2(p.x, p.y), packbf2(p.z, p.w)};
                *(uint2*)&C[(size_t)row * NCOL + cb + 64] = pk2;
            }
        } else {
            float4 o = acc[j][0];
            uint2 pk = {packbf2(o.x, o.y), packbf2(o.z, o.w)};
            *(uint2*)&C[(size_t)row * NCOL + cb] = pk;
            if (NCOL == 128) {
                float4 p = acc[j][1];
                uint2 pk2 = {packbf2(p.x, p.y), packbf2(p.z, p.w)};
                *(uint2*)&C[(size_t)row * NCOL + cb + 64] = pk2;
            }
        }
    }
}

// ---- fused layer-3 aggregate + heads: gather t (64-wide bf16),
//      h4 = nd*agg + b3; PI = h4.Wp + bp; mN partials via padded atomics.
#define HEAD_BLOCKS 784
__global__ __launch_bounds__(256)
void l3head_kernel(const u16* __restrict__ t, const u32* __restrict__ rs,
                   const int* __restrict__ es, const float* __restrict__ nd,
                   const float* __restrict__ b3, const float* __restrict__ Wp,
                   const float* __restrict__ bp, float* __restrict__ out,
                   float* __restrict__ mN) {
    __shared__ float s[64];
    if (threadIdx.x < 64) s[threadIdx.x] = 0.f;
    __syncthreads();
    int lane = threadIdx.x & 63;
    int wv = threadIdx.x >> 6;
    int quarter = lane >> 4;
    int q = lane & 15;
    const uint2* hp = (const uint2*)t;      // row = 16 uint2
    float4 b3v = ((const float4*)b3)[q];
    float4 wpv = ((const float4*)Wp)[q];
    float bpv = bp[0];
    float4 msum = {0.f, 0.f, 0.f, 0.f};
    for (int n = blockIdx.x * 4 + wv; n < N_NODES; n += HEAD_BLOCKS * 4) {
        u32 s0 = rs[n], s1 = rs[n + 1];
        float4 acc = {0.f, 0.f, 0.f, 0.f};
        u32 i = s0;
        for (; i + 8 <= s1; i += 8) {
            int e0 = es[i + quarter], e1 = es[i + 4 + quarter];
            uint2 a = hp[(size_t)e0 * 16 + q];
            uint2 b = hp[(size_t)e1 * 16 + q];
            acc.x += bflo(a.x) + bflo(b.x);
            acc.y += bfhi(a.x) + bfhi(b.x);
            acc.z += bflo(a.y) + bflo(b.y);
            acc.w += bfhi(a.y) + bfhi(b.y);
        }
        for (; i + 4 <= s1; i += 4) {
            int e = es[i + quarter];
            uint2 a = hp[(size_t)e * 16 + q];
            acc.x += bflo(a.x); acc.y += bfhi(a.x);
            acc.z += bflo(a.y); acc.w += bfhi(a.y);
        }
        u32 rem = s1 - i;
        if ((u32)quarter < rem) {
            int e = es[i + quarter];
            uint2 a = hp[(size_t)e * 16 + q];
            acc.x += bflo(a.x); acc.y += bfhi(a.x);
            acc.z += bflo(a.y); acc.w += bfhi(a.y);
        }
        acc.x += __shfl_xor(acc.x, 16, 64); acc.x += __shfl_xor(acc.x, 32, 64);
        acc.y += __shfl_xor(acc.y, 16, 64); acc.y += __shfl_xor(acc.y, 32, 64);
        acc.z += __shfl_xor(acc.z, 16, 64); acc.z += __shfl_xor(acc.z, 32, 64);
        acc.w += __shfl_xor(acc.w, 16, 64); acc.w += __shfl_xor(acc.w, 32, 64);
        float ndv = nd[n];
        float4 h;
        h.x = ndv * acc.x + b3v.x;
        h.y = ndv * acc.y + b3v.y;
        h.z = ndv * acc.z + b3v.z;
        h.w = ndv * acc.w + b3v.w;
        if (lane < 16) {
            msum.x += h.x; msum.y += h.y; msum.z += h.z; msum.w += h.w;
        }
        float p = h.x * wpv.x + h.y * wpv.y + h.z * wpv.z + h.w * wpv.w;
        p += __shfl_xor(p, 1, 64); p += __shfl_xor(p, 2, 64);
        p += __shfl_xor(p, 4, 64); p += __shfl_xor(p, 8, 64);
        if (lane == 0) out[n] = p + bpv;
    }
    if (lane < 16) {
        atomicAdd(&s[q * 4 + 0], msum.x);
        atomicAdd(&s[q * 4 + 1], msum.y);
        atomicAdd(&s[q * 4 + 2], msum.z);
        atomicAdd(&s[q * 4 + 3], msum.w);
    }
    __syncthreads();
    if (threadIdx.x < 64) atomicAdd(&mN[threadIdx.x * 16], s[threadIdx.x]);
}

__global__ void v_kernel(const float* __restrict__ mN, const float* __restrict__ Wv,
                         const float* __restrict__ bv, float* __restrict__ out) {
    int f = threadIdx.x;
    float v = mN[f * 16] * Wv[f];
    #pragma unroll
    for (int off = 32; off; off >>= 1) v += __shfl_down(v, off, 64);
    if (f == 0) out[N_NODES] = v + bv[0];
}

extern "C" void kernel_launch(void* const* d_in, const int* in_sizes, int n_in,
                              void* d_out, int out_size, void* d_ws, size_t ws_size,
                              hipStream_t stream) {
    const float* feat = (const float*)d_in[0];
    const int*   src  = (const int*)d_in[1];
    const int*   dst  = (const int*)d_in[2];
    const float* W0 = (const float*)d_in[3];  const float* b0 = (const float*)d_in[4];
    const float* W1 = (const float*)d_in[5];  const float* b1 = (const float*)d_in[6];
    const float* W2 = (const float*)d_in[7];  const float* b2 = (const float*)d_in[8];
    const float* W3 = (const float*)d_in[9];  const float* b3 = (const float*)d_in[10];
    const float* Wp = (const float*)d_in[11]; const float* bp = (const float*)d_in[12];
    const float* Wv = (const float*)d_in[13]; const float* bv = (const float*)d_in[14];
    float* out = (float*)d_out;
    char*  wsb = (char*)d_ws;

    float* ns    = (float*)(wsb + OFF_NS);
    float* nd    = (float*)(wsb + OFF_ND);
    u32*   rs    = (u32*)(wsb + OFF_RS);
    int*   es    = (int*)(wsb + OFF_ES);
    u32*   cntD  = (u32*)(wsb + OFF_CNTD);
    u32*   cntS  = (u32*)(wsb + OFF_CNTS);
    u32*   totD  = (u32*)(wsb + OFF_TOTD);
    u32*   totS  = (u32*)(wsb + OFF_TOTS);
    u32*   baseD = (u32*)(wsb + OFF_BASED);
    u32*   baseS = (u32*)(wsb + OFF_BASES);
    float* mN    = (float*)(wsb + OFF_MN);
    int2*  db    = (int2*)(wsb + OFF_DB);
    int*   sb    = (int*)(wsb + OFF_SB);
    u16*   T0    = (u16*)(wsb + OFF_T0);
    u16*   T1    = (u16*)(wsb + OFF_T1);
    u16*   TA    = (u16*)(wsb + OFF_TA);
    u16*   Tt    = (u16*)(wsb + OFF_TT);

    hipMemsetAsync(mN, 0, 64 * 16 * sizeof(float), stream);

    p1_kernel<<<NBLK, 256, 0, stream>>>(src, dst, cntD, cntS);
    p2a_kernel<<<NBUK, 256, 0, stream>>>(cntD, cntS, totD, totS);
    p2b_kernel<<<1, 256, 0, stream>>>(totD, totS, baseD, baseS, rs);
    p3_kernel<<<NBLK, 256, 0, stream>>>(src, dst, cntD, cntS, baseD, baseS, db, sb);
    p4d_kernel<<<NBUK, 256, 0, stream>>>(db, totD, baseD, nd, rs, es);
    p4s_kernel<<<NBUK, 256, 0, stream>>>(sb, totS, baseS, ns);

    prescale_kernel<<<6250, 256, 0, stream>>>(feat, ns, T0);

    // layer 0
    agg128_kernel<<<12500, 256, 0, stream>>>(T0, rs, es, TA);
    gemm_kernel<128, 0><<<391, 512, 0, stream>>>(TA, W0, b0, ns, nd, T1);
    // layer 1
    agg128_kernel<<<12500, 256, 0, stream>>>(T1, rs, es, TA);
    gemm_kernel<128, 0><<<391, 512, 0, stream>>>(TA, W1, b1, ns, nd, T0);
    // layer 2
    agg128_kernel<<<12500, 256, 0, stream>>>(T0, rs, es, TA);
    gemm_kernel<128, 0><<<391, 512, 0, stream>>>(TA, W2, b2, ns, nd, T1);  // h3s
    // layer 3: transform first (128->64), then fused aggregate+heads
    gemm_kernel<64, 1><<<391, 512, 0, stream>>>(T1, W3, b3, ns, nd, Tt);
    l3head_kernel<<<HEAD_BLOCKS, 256, 0, stream>>>(Tt, rs, es, nd, b3, Wp, bp, out, mN);
    v_kernel<<<1, 64, 0, stream>>>(mN, Wv, bv, out);
}

// Round 6
// 342.998 us; speedup vs baseline: 2.5480x; 1.2700x over previous
//
#include <hip/hip_runtime.h>
#include <cstddef>

#define N_NODES 50000
#define N_EDGES 800000
#define NBUK    196        // dst/src buckets of 256 nodes
#define NBLK    256        // edge-slice blocks
#define EPB     3125       // edges per slice block (256*3125 = 800000)
#define HEAD_BLOCKS 3136

typedef unsigned u32;
typedef unsigned short u16;
typedef __attribute__((ext_vector_type(8))) short bf16x8;
typedef __attribute__((ext_vector_type(4))) float f32x4;

__device__ __forceinline__ float bflo(u32 u) { return __uint_as_float(u << 16); }
__device__ __forceinline__ float bfhi(u32 u) { return __uint_as_float(u & 0xFFFF0000u); }
__device__ __forceinline__ u32 f2bf(float f) {            // RNE round to bf16
    u32 u = __float_as_uint(f);
    return (u + 0x7FFFu + ((u >> 16) & 1u)) >> 16;
}
__device__ __forceinline__ u32 packbf2(float a, float b) { return f2bf(a) | (f2bf(b) << 16); }

// ---------- byte offsets in workspace ----------
#define OFF_NS    0u          // f32[50000]
#define OFF_ND    200000u     // f32[50000]
#define OFF_RS    400000u     // u32[50001]
#define OFF_ES    600016u     // int[800000]
#define OFF_CNTD  3800016u    // u32[NBLK*NBUK]
#define OFF_CNTS  4000720u    // u32[NBLK*NBUK]
#define OFF_TOTD  4201424u    // u32[NBUK]
#define OFF_TOTS  4202208u    // u32[NBUK]
#define OFF_BASED 4202992u    // u32[NBUK]
#define OFF_BASES 4203776u    // u32[NBUK]
#define OFF_VP    4204560u    // f32[HEAD_BLOCKS] block partials for V
#define OFF_DB    4217104u    // int2[800000]
#define OFF_SB    10617104u   // int [800000]
#define OFF_T0    13817104u   // bf16[50000*128]
#define OFF_T1    26617104u   // bf16[50000*128]
#define OFF_TA    39417104u   // bf16[50000*128]  (agg output)
#define OFF_TT    52217104u   // bf16[50000*64]
// end 58617104 B

// ---- phase 1: per-slice bucket counts (LDS histogram, no global atomics)
__global__ __launch_bounds__(256)
void p1_kernel(const int* __restrict__ src, const int* __restrict__ dst,
               u32* __restrict__ cntD, u32* __restrict__ cntS) {
    __shared__ u32 dc[NBUK], sc[NBUK];
    int b = blockIdx.x, tid = threadIdx.x;
    if (tid < NBUK) { dc[tid] = 0; sc[tid] = 0; }
    __syncthreads();
    int lo = b * EPB, hi = lo + EPB;
    for (int e = lo + tid; e < hi; e += 256) {
        atomicAdd(&dc[dst[e] >> 8], 1u);
        atomicAdd(&sc[src[e] >> 8], 1u);
    }
    __syncthreads();
    if (tid < NBUK) {
        cntD[b * NBUK + tid] = dc[tid];
        cntS[b * NBUK + tid] = sc[tid];
    }
}

// ---- phase 2a: per-bucket scan over the 256 slice counts (in place -> exclusive)
__global__ __launch_bounds__(256)
void p2a_kernel(u32* __restrict__ cntD, u32* __restrict__ cntS,
                u32* __restrict__ totD, u32* __restrict__ totS) {
    __shared__ u32 sc[256];
    int k = blockIdx.x, tid = threadIdx.x;
    u32 v = cntD[tid * NBUK + k];
    sc[tid] = v;
    __syncthreads();
    for (int o = 1; o < 256; o <<= 1) {
        u32 t = (tid >= o) ? sc[tid - o] : 0u;
        __syncthreads(); sc[tid] += t; __syncthreads();
    }
    cntD[tid * NBUK + k] = sc[tid] - v;
    if (tid == 255) totD[k] = sc[255];
    __syncthreads();
    v = cntS[tid * NBUK + k];
    sc[tid] = v;
    __syncthreads();
    for (int o = 1; o < 256; o <<= 1) {
        u32 t = (tid >= o) ? sc[tid - o] : 0u;
        __syncthreads(); sc[tid] += t; __syncthreads();
    }
    cntS[tid * NBUK + k] = sc[tid] - v;
    if (tid == 255) totS[k] = sc[255];
}

// ---- phase 2b: bucket base offsets
__global__ __launch_bounds__(256)
void p2b_kernel(const u32* __restrict__ totD, const u32* __restrict__ totS,
                u32* __restrict__ baseD, u32* __restrict__ baseS, u32* __restrict__ rs) {
    __shared__ u32 sc[256];
    int tid = threadIdx.x;
    u32 v = (tid < NBUK) ? totD[tid] : 0u;
    sc[tid] = v;
    __syncthreads();
    for (int o = 1; o < 256; o <<= 1) {
        u32 t = (tid >= o) ? sc[tid - o] : 0u;
        __syncthreads(); sc[tid] += t; __syncthreads();
    }
    if (tid < NBUK) baseD[tid] = sc[tid] - v;
    __syncthreads();
    v = (tid < NBUK) ? totS[tid] : 0u;
    sc[tid] = v;
    __syncthreads();
    for (int o = 1; o < 256; o <<= 1) {
        u32 t = (tid >= o) ? sc[tid - o] : 0u;
        __syncthreads(); sc[tid] += t; __syncthreads();
    }
    if (tid < NBUK) baseS[tid] = sc[tid] - v;
    if (tid == 0) rs[N_NODES] = N_EDGES;
}

// ---- phase 3: place edges into bucket runs (contiguous per (block,bucket))
__global__ __launch_bounds__(256)
void p3_kernel(const int* __restrict__ src, const int* __restrict__ dst,
               const u32* __restrict__ cntD, const u32* __restrict__ cntS,
               const u32* __restrict__ baseD, const u32* __restrict__ baseS,
               int2* __restrict__ db, int* __restrict__ sb) {
    __shared__ u32 od[NBUK], os[NBUK];
    int b = blockIdx.x, tid = threadIdx.x;
    if (tid < NBUK) {
        od[tid] = baseD[tid] + cntD[b * NBUK + tid];
        os[tid] = baseS[tid] + cntS[b * NBUK + tid];
    }
    __syncthreads();
    int lo = b * EPB, hi = lo + EPB;
    for (int e = lo + tid; e < hi; e += 256) {
        int s = src[e], d = dst[e];
        u32 p = atomicAdd(&od[d >> 8], 1u);
        db[p] = make_int2(s, d);
        u32 q = atomicAdd(&os[s >> 8], 1u);
        sb[q] = s;
    }
}

// ---- phase 4d: per-bucket CSR finalize (in-deg -> nd, rs, es placement)
__global__ __launch_bounds__(256)
void p4d_kernel(const int2* __restrict__ db, const u32* __restrict__ totD,
                const u32* __restrict__ baseD, float* __restrict__ nd,
                u32* __restrict__ rs, int* __restrict__ es) {
    __shared__ u32 hist[256], sc[256], off[256];
    int k = blockIdx.x, tid = threadIdx.x;
    hist[tid] = 0;
    __syncthreads();
    u32 nEd = totD[k], base = baseD[k];
    for (u32 i = tid; i < nEd; i += 256)
        atomicAdd(&hist[db[base + i].y & 255], 1u);
    __syncthreads();
    u32 v = hist[tid];
    sc[tid] = v;
    __syncthreads();
    for (int o = 1; o < 256; o <<= 1) {
        u32 t = (tid >= o) ? sc[tid - o] : 0u;
        __syncthreads(); sc[tid] += t; __syncthreads();
    }
    u32 pf = sc[tid] - v;
    int node = k * 256 + tid;
    if (node < N_NODES) {
        rs[node] = base + pf;
        u32 c = v < 1u ? 1u : v;
        nd[node] = rsqrtf((float)c);
    }
    off[tid] = base + pf;
    __syncthreads();
    for (u32 i = tid; i < nEd; i += 256) {
        int2 p = db[base + i];
        u32 pos = atomicAdd(&off[p.y & 255], 1u);
        es[pos] = p.x;
    }
}

// ---- phase 4s: per-bucket out-degree -> ns
__global__ __launch_bounds__(256)
void p4s_kernel(const int* __restrict__ sb, const u32* __restrict__ totS,
                const u32* __restrict__ baseS, float* __restrict__ ns) {
    __shared__ u32 hist[256];
    int k = blockIdx.x, tid = threadIdx.x;
    hist[tid] = 0;
    __syncthreads();
    u32 n = totS[k], base = baseS[k];
    for (u32 i = tid; i < n; i += 256)
        atomicAdd(&hist[sb[base + i] & 255], 1u);
    __syncthreads();
    int node = k * 256 + tid;
    if (node < N_NODES) {
        u32 c = hist[tid]; if (c < 1u) c = 1u;
        ns[node] = rsqrtf((float)c);
    }
}

// ---- hS(bf16) = feat * ns[row]
__global__ __launch_bounds__(256)
void prescale_kernel(const float* __restrict__ feat, const float* __restrict__ ns,
                     u16* __restrict__ hS) {
    int i = blockIdx.x * 256 + threadIdx.x;      // over N_NODES*32 float4 chunks
    if (i < N_NODES * 32) {
        float s = ns[i >> 5];
        float4 v = *(const float4*)&feat[(size_t)i * 4];
        uint2 o;
        o.x = packbf2(s * v.x, s * v.y);
        o.y = packbf2(s * v.z, s * v.w);
        *(uint2*)&hS[(size_t)i * 4] = o;
    }
}

// ---- 128-wide bf16 gather-aggregate, bf16 out; 1 wave/node,
//      quarter-wave = 1 edge row (16 lanes x uint4 = 256B), 16 edges/main iter
__global__ __launch_bounds__(256)
void agg128_kernel(const u16* __restrict__ h, const u32* __restrict__ rs,
                   const int* __restrict__ es, u16* __restrict__ agg) {
    int node = blockIdx.x * 4 + (threadIdx.x >> 6);
    int lane = threadIdx.x & 63;
    int quarter = lane >> 4;
    int q = lane & 15;                    // uint4 chunk (8 bf16) within row
    const uint4* hp = (const uint4*)h;    // row = 16 uint4
    u32 s0 = rs[node], s1 = rs[node + 1];
    float acc[8] = {0.f, 0.f, 0.f, 0.f, 0.f, 0.f, 0.f, 0.f};
    u32 i = s0;
    for (; i + 16 <= s1; i += 16) {
        int e0 = es[i + quarter],     e1 = es[i + 4 + quarter];
        int e2 = es[i + 8 + quarter], e3 = es[i + 12 + quarter];
        uint4 a = hp[(size_t)e0 * 16 + q];
        uint4 b = hp[(size_t)e1 * 16 + q];
        uint4 c = hp[(size_t)e2 * 16 + q];
        uint4 d = hp[(size_t)e3 * 16 + q];
        acc[0] += (bflo(a.x) + bflo(b.x)) + (bflo(c.x) + bflo(d.x));
        acc[1] += (bfhi(a.x) + bfhi(b.x)) + (bfhi(c.x) + bfhi(d.x));
        acc[2] += (bflo(a.y) + bflo(b.y)) + (bflo(c.y) + bflo(d.y));
        acc[3] += (bfhi(a.y) + bfhi(b.y)) + (bfhi(c.y) + bfhi(d.y));
        acc[4] += (bflo(a.z) + bflo(b.z)) + (bflo(c.z) + bflo(d.z));
        acc[5] += (bfhi(a.z) + bfhi(b.z)) + (bfhi(c.z) + bfhi(d.z));
        acc[6] += (bflo(a.w) + bflo(b.w)) + (bflo(c.w) + bflo(d.w));
        acc[7] += (bfhi(a.w) + bfhi(b.w)) + (bfhi(c.w) + bfhi(d.w));
    }
    for (; i + 4 <= s1; i += 4) {
        uint4 a = hp[(size_t)es[i + quarter] * 16 + q];
        acc[0] += bflo(a.x); acc[1] += bfhi(a.x);
        acc[2] += bflo(a.y); acc[3] += bfhi(a.y);
        acc[4] += bflo(a.z); acc[5] += bfhi(a.z);
        acc[6] += bflo(a.w); acc[7] += bfhi(a.w);
    }
    u32 rem = s1 - i;
    if ((u32)quarter < rem) {
        uint4 a = hp[(size_t)es[i + quarter] * 16 + q];
        acc[0] += bflo(a.x); acc[1] += bfhi(a.x);
        acc[2] += bflo(a.y); acc[3] += bfhi(a.y);
        acc[4] += bflo(a.z); acc[5] += bfhi(a.z);
        acc[6] += bflo(a.w); acc[7] += bfhi(a.w);
    }
    #pragma unroll
    for (int j = 0; j < 8; ++j) {
        acc[j] += __shfl_xor(acc[j], 16, 64);
        acc[j] += __shfl_xor(acc[j], 32, 64);
    }
    if (lane < 16) {
        uint4 pk;
        pk.x = packbf2(acc[0], acc[1]);
        pk.y = packbf2(acc[2], acc[3]);
        pk.z = packbf2(acc[4], acc[5]);
        pk.w = packbf2(acc[6], acc[7]);
        *(uint4*)&agg[(size_t)node * 128 + q * 8] = pk;
    }
}

// ---- MFMA GEMM: A bf16 [50000][128], W f32 [128][NCOL] -> C bf16 [50000][NCOL]
// block = 256 thr (4 waves), 64 rows/block; wave = 16 rows x NCOL.
// MODE 0: C = ns*relu(nd*acc + b); MODE 1: C = acc
template <int NCOL, int MODE>
__global__ __launch_bounds__(256)
void mfma_gemm_kernel(const u16* __restrict__ Ab, const float* __restrict__ W,
                      const float* __restrict__ bias, const float* __restrict__ ns,
                      const float* __restrict__ nd, u16* __restrict__ C) {
    constexpr int NT = NCOL / 16;          // MFMA n-tiles per wave
    constexpr int WROW = 136;              // u16 row stride (+8 pad: 2-way only)
    constexpr int CROW = NCOL + 4;         // f32 row stride of C staging
    __shared__ u16 Wt[NCOL * WROW];        // W transposed: Wt[c][k]
    __shared__ float Cl[4][16 * CROW];
    int tid = threadIdx.x;
    int w = tid >> 6, lane = tid & 63;
    int rowbase = blockIdx.x * 64 + w * 16;

    // stage Wt[c][k] = bf16(W[k][c]) — read coalesced, scatter to LDS
    for (int i = tid; i < 128 * NCOL; i += 256) {
        int k = i / NCOL, c = i % NCOL;
        Wt[c * WROW + k] = (u16)f2bf(W[i]);
    }
    __syncthreads();

    int m = lane & 15, kb = lane >> 4;     // A row / k-block within 32-k step
    int arow = rowbase + m;
    if (arow > N_NODES - 1) arow = N_NODES - 1;   // clamp (invalid rows unstored)
    f32x4 acc[NT];
    #pragma unroll
    for (int nt = 0; nt < NT; ++nt) acc[nt] = (f32x4){0.f, 0.f, 0.f, 0.f};

    #pragma unroll
    for (int ks = 0; ks < 4; ++ks) {       // K = 128 = 4 x 32
        int k0 = ks * 32 + kb * 8;
        bf16x8 a = *(const bf16x8*)&Ab[(size_t)arow * 128 + k0];
        #pragma unroll
        for (int nt = 0; nt < NT; ++nt) {
            bf16x8 b = *(const bf16x8*)&Wt[(nt * 16 + m) * WROW + k0];
            acc[nt] = __builtin_amdgcn_mfma_f32_16x16x32_bf16(a, b, acc[nt], 0, 0, 0);
        }
    }

    // stage C tile: D layout col = lane&15 (m), row = kb*4 + reg (m89-verified)
    #pragma unroll
    for (int nt = 0; nt < NT; ++nt)
        #pragma unroll
        for (int reg = 0; reg < 4; ++reg)
            Cl[w][(kb * 4 + reg) * CROW + nt * 16 + m] = acc[nt][reg];
    __syncthreads();

    // epilogue: coalesced read-back, scale/bias/relu, packed bf16 store
    constexpr int CQ = NCOL / 4;
    for (int i = lane; i < 16 * CQ; i += 64) {
        int r = i / CQ, c4 = (i % CQ) * 4;
        int row = rowbase + r;
        if (row < N_NODES) {
            float4 o = *(float4*)&Cl[w][r * CROW + c4];
            if (MODE == 0) {
                float sd = nd[row], ss = ns[row];
                o.x = ss * fmaxf(sd * o.x + bias[c4 + 0], 0.f);
                o.y = ss * fmaxf(sd * o.y + bias[c4 + 1], 0.f);
                o.z = ss * fmaxf(sd * o.z + bias[c4 + 2], 0.f);
                o.w = ss * fmaxf(sd * o.w + bias[c4 + 3], 0.f);
            }
            uint2 pk = {packbf2(o.x, o.y), packbf2(o.z, o.w)};
            *(uint2*)&C[(size_t)row * NCOL + c4] = pk;
        }
    }
}

// ---- fused layer-3 aggregate + heads: gather t (64-wide bf16),
//      h4 = nd*agg + b3; PI = h4.Wp + bp; V partial = sum h4.Wv per block.
__global__ __launch_bounds__(256)
void l3head_kernel(const u16* __restrict__ t, const u32* __restrict__ rs,
                   const int* __restrict__ es, const float* __restrict__ nd,
                   const float* __restrict__ b3, const float* __restrict__ Wp,
                   const float* __restrict__ Wv, const float* __restrict__ bp,
                   float* __restrict__ out, float* __restrict__ vpart) {
    __shared__ float sv;
    if (threadIdx.x == 0) sv = 0.f;
    __syncthreads();
    int lane = threadIdx.x & 63;
    int wvid = threadIdx.x >> 6;
    int quarter = lane >> 4;
    int q = lane & 15;
    const uint2* hp = (const uint2*)t;      // row = 16 uint2
    float4 b3v = ((const float4*)b3)[q];
    float4 wpv = ((const float4*)Wp)[q];
    float4 wvv = ((const float4*)Wv)[q];
    float bpv = bp[0];
    float vacc = 0.f;
    for (int n = blockIdx.x * 4 + wvid; n < N_NODES; n += HEAD_BLOCKS * 4) {
        u32 s0 = rs[n], s1 = rs[n + 1];
        float4 acc = {0.f, 0.f, 0.f, 0.f};
        u32 i = s0;
        for (; i + 8 <= s1; i += 8) {
            int e0 = es[i + quarter], e1 = es[i + 4 + quarter];
            uint2 a = hp[(size_t)e0 * 16 + q];
            uint2 b = hp[(size_t)e1 * 16 + q];
            acc.x += bflo(a.x) + bflo(b.x);
            acc.y += bfhi(a.x) + bfhi(b.x);
            acc.z += bflo(a.y) + bflo(b.y);
            acc.w += bfhi(a.y) + bfhi(b.y);
        }
        for (; i + 4 <= s1; i += 4) {
            int e = es[i + quarter];
            uint2 a = hp[(size_t)e * 16 + q];
            acc.x += bflo(a.x); acc.y += bfhi(a.x);
            acc.z += bflo(a.y); acc.w += bfhi(a.y);
        }
        u32 rem = s1 - i;
        if ((u32)quarter < rem) {
            int e = es[i + quarter];
            uint2 a = hp[(size_t)e * 16 + q];
            acc.x += bflo(a.x); acc.y += bfhi(a.x);
            acc.z += bflo(a.y); acc.w += bfhi(a.y);
        }
        acc.x += __shfl_xor(acc.x, 16, 64); acc.x += __shfl_xor(acc.x, 32, 64);
        acc.y += __shfl_xor(acc.y, 16, 64); acc.y += __shfl_xor(acc.y, 32, 64);
        acc.z += __shfl_xor(acc.z, 16, 64); acc.z += __shfl_xor(acc.z, 32, 64);
        acc.w += __shfl_xor(acc.w, 16, 64); acc.w += __shfl_xor(acc.w, 32, 64);
        float ndv = nd[n];
        float4 h;
        h.x = ndv * acc.x + b3v.x;
        h.y = ndv * acc.y + b3v.y;
        h.z = ndv * acc.z + b3v.z;
        h.w = ndv * acc.w + b3v.w;
        float p  = h.x * wpv.x + h.y * wpv.y + h.z * wpv.z + h.w * wpv.w;
        float vv = h.x * wvv.x + h.y * wvv.y + h.z * wvv.z + h.w * wvv.w;
        p  += __shfl_xor(p, 1, 64);  p  += __shfl_xor(p, 2, 64);
        p  += __shfl_xor(p, 4, 64);  p  += __shfl_xor(p, 8, 64);
        vv += __shfl_xor(vv, 1, 64); vv += __shfl_xor(vv, 2, 64);
        vv += __shfl_xor(vv, 4, 64); vv += __shfl_xor(vv, 8, 64);
        if (lane == 0) { out[n] = p + bpv; vacc += vv; }
    }
    if (lane == 0) atomicAdd(&sv, vacc);
    __syncthreads();
    if (threadIdx.x == 0) vpart[blockIdx.x] = sv;
}

// ---- final V reduction over block partials
__global__ __launch_bounds__(256)
void vred_kernel(const float* __restrict__ vpart, const float* __restrict__ bv,
                 float* __restrict__ out) {
    float v = 0.f;
    for (int i = threadIdx.x; i < HEAD_BLOCKS; i += 256) v += vpart[i];
    #pragma unroll
    for (int off = 32; off; off >>= 1) v += __shfl_down(v, off, 64);
    __shared__ float s[4];
    if ((threadIdx.x & 63) == 0) s[threadIdx.x >> 6] = v;
    __syncthreads();
    if (threadIdx.x == 0) out[N_NODES] = s[0] + s[1] + s[2] + s[3] + bv[0];
}

extern "C" void kernel_launch(void* const* d_in, const int* in_sizes, int n_in,
                              void* d_out, int out_size, void* d_ws, size_t ws_size,
                              hipStream_t stream) {
    const float* feat = (const float*)d_in[0];
    const int*   src  = (const int*)d_in[1];
    const int*   dst  = (const int*)d_in[2];
    const float* W0 = (const float*)d_in[3];  const float* b0 = (const float*)d_in[4];
    const float* W1 = (const float*)d_in[5];  const float* b1 = (const float*)d_in[6];
    const float* W2 = (const float*)d_in[7];  const float* b2 = (const float*)d_in[8];
    const float* W3 = (const float*)d_in[9];  const float* b3 = (const float*)d_in[10];
    const float* Wp = (const float*)d_in[11]; const float* bp = (const float*)d_in[12];
    const float* Wv = (const float*)d_in[13]; const float* bv = (const float*)d_in[14];
    float* out = (float*)d_out;
    char*  wsb = (char*)d_ws;

    float* ns    = (float*)(wsb + OFF_NS);
    float* nd    = (float*)(wsb + OFF_ND);
    u32*   rs    = (u32*)(wsb + OFF_RS);
    int*   es    = (int*)(wsb + OFF_ES);
    u32*   cntD  = (u32*)(wsb + OFF_CNTD);
    u32*   cntS  = (u32*)(wsb + OFF_CNTS);
    u32*   totD  = (u32*)(wsb + OFF_TOTD);
    u32*   totS  = (u32*)(wsb + OFF_TOTS);
    u32*   baseD = (u32*)(wsb + OFF_BASED);
    u32*   baseS = (u32*)(wsb + OFF_BASES);
    float* vpart = (float*)(wsb + OFF_VP);
    int2*  db    = (int2*)(wsb + OFF_DB);
    int*   sb    = (int*)(wsb + OFF_SB);
    u16*   T0    = (u16*)(wsb + OFF_T0);
    u16*   T1    = (u16*)(wsb + OFF_T1);
    u16*   TA    = (u16*)(wsb + OFF_TA);
    u16*   Tt    = (u16*)(wsb + OFF_TT);

    p1_kernel<<<NBLK, 256, 0, stream>>>(src, dst, cntD, cntS);
    p2a_kernel<<<NBUK, 256, 0, stream>>>(cntD, cntS, totD, totS);
    p2b_kernel<<<1, 256, 0, stream>>>(totD, totS, baseD, baseS, rs);
    p3_kernel<<<NBLK, 256, 0, stream>>>(src, dst, cntD, cntS, baseD, baseS, db, sb);
    p4d_kernel<<<NBUK, 256, 0, stream>>>(db, totD, baseD, nd, rs, es);
    p4s_kernel<<<NBUK, 256, 0, stream>>>(sb, totS, baseS, ns);

    prescale_kernel<<<6250, 256, 0, stream>>>(feat, ns, T0);

    // layer 0
    agg128_kernel<<<12500, 256, 0, stream>>>(T0, rs, es, TA);
    mfma_gemm_kernel<128, 0><<<782, 256, 0, stream>>>(TA, W0, b0, ns, nd, T1);
    // layer 1
    agg128_kernel<<<12500, 256, 0, stream>>>(T1, rs, es, TA);
    mfma_gemm_kernel<128, 0><<<782, 256, 0, stream>>>(TA, W1, b1, ns, nd, T0);
    // layer 2
    agg128_kernel<<<12500, 256, 0, stream>>>(T0, rs, es, TA);
    mfma_gemm_kernel<128, 0><<<782, 256, 0, stream>>>(TA, W2, b2, ns, nd, T1);  // h3s
    // layer 3: transform first (128->64), then fused aggregate+heads
    mfma_gemm_kernel<64, 1><<<782, 256, 0, stream>>>(T1, W3, b3, ns, nd, Tt);
    l3head_kernel<<<HEAD_BLOCKS, 256, 0, stream>>>(Tt, rs, es, nd, b3, Wp, Wv, bp, out, vpart);
    vred_kernel<<<1, 256, 0, stream>>>(vpart, bv, out);
}